// Round 17
// baseline (585.229 us; speedup 1.0000x reference)
//
#include <hip/hip_runtime.h>
#include <hip/hip_bf16.h>

typedef short bf16x8 __attribute__((ext_vector_type(8)));
typedef float f32x4  __attribute__((ext_vector_type(4)));
typedef unsigned short u16;

#define B_N 4
#define C_N 128
#define HW_ 256
#define NPIX 65536
#define NK 396
#define NKP 400
#define OUT_MAIN ((size_t)B_N * C_N * NPIX)
#define P12_OFF OUT_MAIN
#define P6_OFF  (P12_OFF + (size_t)B_N * C_N * 144)

// attn LDS arena: two 32KB buffers (K 16KB + VT 16KB each); no P region
#define BUFSZ  32768
#define VT_OFF 16384
#define LDS_BYTES 65536

static __device__ __forceinline__ u16 f2bf(float x) {
  __hip_bfloat16 h = __float2bfloat16(x);
  return *(u16*)&h;
}
static __device__ __forceinline__ unsigned pack2(float lo, float hi) {
  return ((unsigned)f2bf(hi) << 16) | f2bf(lo);
}
static __device__ __forceinline__ void gl_lds16(const void* g, void* l) {
  __builtin_amdgcn_global_load_lds(
      (const __attribute__((address_space(1))) unsigned*)g,
      (__attribute__((address_space(3))) unsigned*)l, 16, 0, 0);
}
#define MFMA32 __builtin_amdgcn_mfma_f32_16x16x32_bf16
#define BAR() do { __builtin_amdgcn_s_barrier(); \
                   __builtin_amdgcn_sched_barrier(0); } while (0)
#define VM4() do { asm volatile("s_waitcnt vmcnt(4)" ::: "memory"); \
                   __builtin_amdgcn_sched_barrier(0); } while (0)
#define VM2() do { asm volatile("s_waitcnt vmcnt(2)" ::: "memory"); \
                   __builtin_amdgcn_sched_barrier(0); } while (0)

// ---- pool Phase A body, H0 compile-time: all segment math constant-folds ----
template<int H0>
static __device__ __forceinline__ void pool_phaseA(
    const float2* __restrict__ plane2, float (*yh)[257], int w2)
{
  const int os_[7] = {16,12,9,7,6,3,1};
  const int ro_[7] = {0,16,28,37,44,50,53};
  float ax[7], ay[7], a2x[7], a2y[7], inv_[7];
  int r_[7], e_[7], s2_[7];
  #pragma unroll
  for (int s = 0; s < 7; ++s) {
    const int o = os_[s];
    const int r = (H0 * o) >> 8;
    const int sr = (r * 256) / o;
    r_[s]  = r;
    e_[s]  = ((r + 1) * 256 + o - 1) / o;
    s2_[s] = ((r + 1) * 256) / o;
    inv_[s] = 1.0f / (float)(e_[s] - sr);
    ax[s] = 0.f; ay[s] = 0.f; a2x[s] = 0.f; a2y[s] = 0.f;
  }
  #pragma unroll
  for (int g = 0; g < 4; ++g) {
    float2 vv[8];
    #pragma unroll
    for (int k = 0; k < 8; ++k) vv[k] = plane2[(H0 + g*8 + k) * 128 + w2];
    #pragma unroll
    for (int k = 0; k < 8; ++k) {
      const int h = H0 + g*8 + k;
      const float2 v = vv[k];
      #pragma unroll
      for (int s = 0; s < 7; ++s) {
        const int o = os_[s];
        ax[s] += v.x; ay[s] += v.y;
        if (h >= s2_[s]) { a2x[s] += v.x; a2y[s] += v.y; }
        if (h + 1 == e_[s]) {
          atomicAdd(&yh[ro_[s] + r_[s]][2*w2],     ax[s] * inv_[s]);
          atomicAdd(&yh[ro_[s] + r_[s]][2*w2 + 1], ay[s] * inv_[s]);
          r_[s]++;
          const int sr = s2_[s];
          e_[s]  = ((r_[s] + 1) * 256 + o - 1) / o;
          s2_[s] = ((r_[s] + 1) * 256) / o;
          inv_[s] = 1.0f / (float)(e_[s] - sr);
          ax[s] = a2x[s]; ay[s] = a2y[s];
          a2x[s] = 0.f; a2y[s] = 0.f;
        }
      }
    }
  }
  // flush in-progress segments (partials for segments crossing chunk end)
  #pragma unroll
  for (int s = 0; s < 7; ++s) {
    const int o = os_[s];
    if (r_[s] < o) {
      atomicAdd(&yh[ro_[s] + r_[s]][2*w2],     ax[s] * inv_[s]);
      atomicAdd(&yh[ro_[s] + r_[s]][2*w2 + 1], ay[s] * inv_[s]);
      if (r_[s] + 1 < o && s2_[s] < H0 + 32) {
        const int sr2 = s2_[s];
        const int e2  = ((r_[s] + 2) * 256 + o - 1) / o;
        const float inv2 = 1.0f / (float)(e2 - sr2);
        atomicAdd(&yh[ro_[s] + r_[s] + 1][2*w2],     a2x[s] * inv2);
        atomicAdd(&yh[ro_[s] + r_[s] + 1][2*w2 + 1], a2y[s] * inv2);
      }
    }
  }
}

// ---------------- kernel 1: multi-scale adaptive avg pools ----------------
__global__ __launch_bounds__(1024) void pool_kernel(
    const float* __restrict__ x5, const float* __restrict__ W_out,
    u16* __restrict__ wsK, u16* __restrict__ wsKT, u16* __restrict__ wsW,
    float* __restrict__ out)
{
  __shared__ float yh[54][257];
  const int tid = threadIdx.x;
  const int bc = blockIdx.x;          // b*128+c
  const int b  = bc >> 7;
  const int c  = bc & 127;
  const float2* plane2 = (const float2*)(x5 + (size_t)bc * NPIX);
  const int w2 = tid & 127;           // columns 2*w2, 2*w2+1
  const int q  = tid >> 7;            // row chunk 0..7 (wave-uniform)

  if (bc < 16) {                      // W f32 -> bf16, conv-fragment column perm
    const int idx = bc * 1024 + tid;
    const int o = idx >> 7, pp = idx & 127;
    const int q32 = pp >> 5, pos = pp & 31, g = pos >> 3, jj = pos & 7;
    const int csrc = q32 * 32 + ((jj < 4) ? (g * 4 + jj) : (16 + g * 4 + (jj - 4)));
    wsW[idx] = f2bf(W_out[o * 128 + csrc]);
  }

  // zero the accumulator tile
  for (int i = tid; i < 54 * 257; i += 1024) ((float*)yh)[i] = 0.f;
  __syncthreads();

  switch (q) {
    case 0: pool_phaseA<0>  (plane2, yh, w2); break;
    case 1: pool_phaseA<32> (plane2, yh, w2); break;
    case 2: pool_phaseA<64> (plane2, yh, w2); break;
    case 3: pool_phaseA<96> (plane2, yh, w2); break;
    case 4: pool_phaseA<128>(plane2, yh, w2); break;
    case 5: pool_phaseA<160>(plane2, yh, w2); break;
    case 6: pool_phaseA<192>(plane2, yh, w2); break;
    default: pool_phaseA<224>(plane2, yh, w2); break;
  }
  __syncthreads();

  // zero key-padding 396..399
  if (tid < NKP - NK) {
    wsK [((size_t)b * NKP + NK + tid) * C_N + c] = 0;
    wsKT[(size_t)bc * NKP + NK + tid] = 0;
  }

  // Phase B: 64 groups of 16 lanes; each group reduces one output per iter
  const int grp = tid >> 4;
  const int gl  = tid & 15;
  #pragma unroll
  for (int it = 0; it < 9; ++it) {
    const int r = grp + it * 64;
    int rr = r;
    int o, ro, kbase, dst;   // dst: 0=Key, 1=p12, 2=p6
    if      (rr < 256) { o = 16; ro = 0;  kbase = 140; dst = 0; }
    else if (rr < 400) { o = 12; ro = 16; kbase = 0;   dst = 1; rr -= 256; }
    else if (rr < 481) { o = 9;  ro = 28; kbase = 10;  dst = 0; rr -= 400; }
    else if (rr < 530) { o = 7;  ro = 37; kbase = 91;  dst = 0; rr -= 481; }
    else if (rr < 566) { o = 6;  ro = 44; kbase = 0;   dst = 2; rr -= 530; }
    else if (rr < 575) { o = 3;  ro = 50; kbase = 0;   dst = 0; rr -= 566; }
    else               { o = 1;  ro = 53; kbase = 9;   dst = 0; rr = 0;   }
    const int i = rr / o;
    const int j = rr - i * o;
    const int s = (j * HW_) / o;
    const int e = ((j + 1) * HW_ + o - 1) / o;
    float partial = 0.f;
    const float* row = yh[ro + i];
    for (int wq = s + gl; wq < e; wq += 16) partial += row[wq];
    partial += __shfl_xor(partial, 1);
    partial += __shfl_xor(partial, 2);
    partial += __shfl_xor(partial, 4);
    partial += __shfl_xor(partial, 8);
    if (gl == 0) {
      const float v = partial * (1.0f / (float)(e - s));
      if (dst == 1) {
        out[P12_OFF + (size_t)bc * 144 + rr] = v;
      } else if (dst == 2) {
        out[P6_OFF + (size_t)bc * 36 + rr] = v;
      } else {
        const int key = kbase + rr;
        const u16 bv = f2bf(v);
        wsK [((size_t)b * NKP + key) * C_N + c] = bv;   // [b][key][c]
        wsKT[(size_t)bc * NKP + key]            = bv;   // [b][c][key]
      }
    }
  }
}

// ---------------- attn staging helpers (512 threads = 8 waves) ------------
// K rows staged PERMUTED: tile j, row rit holds key CB + (j>>1)*32 +
// 8*(rit>>2) + (j&1)*4 + (rit&3) -> lane's 8 scores over a tile pair are
// keys 8*l4..8*l4+7 (natural order); P fragment assembles lane-locally.
// 8 waves: each wave issues 2 K-ops + 2 VT-ops per chunk (4 loads).
template<int CB, int BUF>
static __device__ __forceinline__ void stage64(
    char* smem, const char* wsKb, const char* wsKTb, int wv, int lane)
{
  char* buf = smem + BUF * BUFSZ;
  const int lr = lane >> 4, lc = lane & 15;
  #pragma unroll
  for (int t = 0; t < 2; ++t) {
    const int op  = wv * 2 + t;                 // 0..15
    const int j   = op >> 2;                    // K tile
    const int rb  = (op & 3) * 4;               // row base in tile
    const int rit = rb + lr;
    const int gk  = CB + (j >> 1) * 32 + 8 * (rb >> 2) + ((j & 1) << 2) + lr;
    gl_lds16(wsKb + (size_t)gk * 256 + ((lc ^ rit) << 4),
             buf + j * 4096 + rb * 256);
    const int vrow = op * 8 + (lane >> 3);      // 128 c rows x 128B
    gl_lds16(wsKTb + (size_t)vrow * (NKP*2) + CB*2 + (((lane & 7) ^ (vrow & 7)) << 4),
             buf + VT_OFF + op * 1024);
  }
}

static __device__ __forceinline__ void stage_tail(
    char* buf, const char* wsKb, const char* wsKTb, int wv, int lane)
{
  const int lr = lane >> 4, lc = lane & 15;
  #pragma unroll
  for (int t = 0; t < 2; ++t) {
    const int op = wv * 2 + t;                  // 0..15 (wave-uniform branch)
    if (op < 8) {          // K: 2 permuted tiles; keys >=396 zeroed/masked
      const int j = op >> 2, rb = (op & 3) * 4;
      const int rit = rb + lr;
      const int gk = 384 + 8 * (rb >> 2) + ((j & 1) << 2) + lr;
      gl_lds16(wsKb + (size_t)gk * 256 + ((lc ^ rit) << 4),
               buf + j * 4096 + rb * 256);
    } else {               // VT: 128 rows x 64B (32B real + 32B overread)
      const int v = op - 8;
      const int row = v * 16 + (lane >> 2);
      gl_lds16(wsKTb + (size_t)row * (NKP*2) + 768 + ((lane & 3) << 4),
               buf + VT_OFF + v * 1024);
    }
  }
}

static __device__ __forceinline__ void stage_W(
    char* smem, const u16* wsW, int wv, int lane)
{
  const int lr = lane >> 4, lc = lane & 15;
  #pragma unroll
  for (int t = 0; t < 4; ++t) {   // 128 rows x 256B bf16 -> buf1
    const int op = wv * 4 + t;    // 0..31
    const int row = op * 4 + lr;
    gl_lds16((const char*)wsW + (size_t)row * 256 + ((lc ^ (row & 15)) << 4),
             smem + BUFSZ + op * 1024);
  }
}

// ------ per-64-key chunk: QK^T -> exp -> PV; P stays in registers --------
template<int BUF, int TAIL>
static __device__ __forceinline__ void compute64(
    char* smem, const bf16x8 (&qf)[2][4],
    f32x4 (&agg)[8][2], float (&d)[2], int l15, int l4)
{
  const char* buf = smem + BUF * BUFSZ;
  constexpr int NT   = TAIL ? 2 : 4;
  constexpr int SUBS = TAIL ? 1 : 2;

  f32x4 sA[NT][2];
  #pragma unroll
  for (int nt = 0; nt < NT; ++nt) {
    sA[nt][0] = (f32x4){0.f,0.f,0.f,0.f};
    sA[nt][1] = (f32x4){0.f,0.f,0.f,0.f};
  }
  #pragma unroll
  for (int nt = 0; nt < NT; ++nt) {
    bf16x8 kf[4];
    #pragma unroll
    for (int kc = 0; kc < 4; ++kc)
      kf[kc] = *(const bf16x8*)(buf + (nt*16 + l15) * 256 +
                                ((kc*64 + l4*16) ^ (l15 << 4)));
    #pragma unroll
    for (int kc = 0; kc < 4; ++kc) {
      sA[nt][0] = MFMA32(kf[kc], qf[0][kc], sA[nt][0], 0, 0, 0);
      sA[nt][1] = MFMA32(kf[kc], qf[1][kc], sA[nt][1], 0, 0, 0);
    }
  }

  #pragma unroll
  for (int sub = 0; sub < SUBS; ++sub) {
    bf16x8 pf[2];
    #pragma unroll
    for (int pt = 0; pt < 2; ++pt) {
      float e[8];
      #pragma unroll
      for (int qi = 0; qi < 4; ++qi) e[qi]     = exp2f(sA[2*sub][pt][qi]);
      #pragma unroll
      for (int qi = 0; qi < 4; ++qi) e[4 + qi] = exp2f(sA[2*sub + 1][pt][qi]);
      if (TAIL) {
        #pragma unroll
        for (int j = 0; j < 8; ++j) if (l4*8 + j >= 12) e[j] = 0.f;
      }
      d[pt] += ((e[0]+e[1]) + (e[2]+e[3])) + ((e[4]+e[5]) + (e[6]+e[7]));
      bf16x8 t;
      #pragma unroll
      for (int j = 0; j < 8; ++j) t[j] = (short)f2bf(e[j]);
      pf[pt] = t;
    }
    #pragma unroll
    for (int ct = 0; ct < 8; ++ct) {
      const int vrow = ct*16 + l15;
      bf16x8 vf;
      if (TAIL)
        vf = *(const bf16x8*)(buf + VT_OFF + vrow*64 + l4*16);
      else
        vf = *(const bf16x8*)(buf + VT_OFF + vrow*128 +
                              ((sub*64 + l4*16) ^ ((vrow & 7) << 4)));
      agg[ct][0] = MFMA32(vf, pf[0], agg[ct][0], 0, 0, 0);
      agg[ct][1] = MFMA32(vf, pf[1], agg[ct][1], 0, 0, 0);
    }
  }
}

// -------- kernel 2: MFMA attention + 1x1 conv + bias + residual --------
__global__ __launch_bounds__(512, 4) void attn_kernel(
    const float* __restrict__ x5, const u16* __restrict__ wsK,
    const u16* __restrict__ wsKT, const u16* __restrict__ wsW,
    const float* __restrict__ b_out, float* __restrict__ out)
{
  extern __shared__ char smem[];
  const int tid  = threadIdx.x;
  // bijective XCD swizzle: 1024 blocks, 8 XCDs, 128 contiguous per XCD
  const int wgid = (blockIdx.x & 7) * 128 + (blockIdx.x >> 3);
  const int b    = wgid >> 8;
  const int pix0 = (wgid & 255) << 8;           // 256 pixels per block
  const int lane = tid & 63, wv = tid >> 6;     // 8 waves
  const int l15  = lane & 15, l4 = lane >> 4;
  const float SCL2 = 0.044194173824159216f * 1.4426950408889634f;

  const char* wsKb  = (const char*)wsK  + (size_t)b * NKP * C_N * 2;
  const char* wsKTb = (const char*)wsKT + (size_t)b * C_N * NKP * 2;

  // ---- stage Q [256 pix][128 c] bf16 into buf0+buf1 (scale folded in) ----
  {
    const float* r0p = x5 + (((size_t)(b * C_N + 2*lane)) << 16) + pix0 + wv * 32;
    const float* r1p = r0p + NPIX;
    float4 v0[8], v1[8];
    #pragma unroll
    for (int j = 0; j < 8; ++j) {
      v0[j] = *(const float4*)(r0p + j*4);
      v1[j] = *(const float4*)(r1p + j*4);
    }
    #pragma unroll
    for (int i = 0; i < 32; ++i) {
      const int pix = wv * 32 + i;
      const unsigned pk = pack2(((const float*)&v0[i>>2])[i&3] * SCL2,
                                ((const float*)&v1[i>>2])[i&3] * SCL2);
      *(unsigned*)(smem + pix * 256 + ((lane*4) ^ ((pix & 15) << 4))) = pk;
    }
  }
  __syncthreads();

  bf16x8 qf[2][4];
  #pragma unroll
  for (int pt = 0; pt < 2; ++pt)
    #pragma unroll
    for (int kc = 0; kc < 4; ++kc)
      qf[pt][kc] = *(const bf16x8*)(smem + (wv*32 + pt*16 + l15) * 256 +
                                    ((kc*64 + l4*16) ^ (l15 << 4)));
  __syncthreads();

  f32x4 agg[8][2];
  #pragma unroll
  for (int ct = 0; ct < 8; ++ct) {
    agg[ct][0] = (f32x4){0.f,0.f,0.f,0.f};
    agg[ct][1] = (f32x4){0.f,0.f,0.f,0.f};
  }
  float d[2] = {0.f, 0.f};

  // ---- chunk pipeline: counted vmcnt keeps next-chunk loads in flight ----
  stage64<0, 0>(smem, wsKb, wsKTb, wv, lane);
  stage64<64, 1>(smem, wsKb, wsKTb, wv, lane);
  VM4(); BAR();                                  // chunk0 landed; chunk1 flying
  compute64<0, 0>(smem, qf, agg, d, l15, l4);
  BAR();                                         // all waves done reading buf0

  stage64<128, 0>(smem, wsKb, wsKTb, wv, lane);
  VM4(); BAR();
  compute64<1, 0>(smem, qf, agg, d, l15, l4);
  BAR();

  stage64<192, 1>(smem, wsKb, wsKTb, wv, lane);
  VM4(); BAR();
  compute64<0, 0>(smem, qf, agg, d, l15, l4);
  BAR();

  stage64<256, 0>(smem, wsKb, wsKTb, wv, lane);
  VM4(); BAR();
  compute64<1, 0>(smem, qf, agg, d, l15, l4);
  BAR();

  stage64<320, 1>(smem, wsKb, wsKTb, wv, lane);
  VM4(); BAR();
  compute64<0, 0>(smem, qf, agg, d, l15, l4);
  BAR();

  stage_tail(smem, wsKb, wsKTb, wv, lane);       // tail -> buf0 (2 loads/wave)
  VM2(); BAR();                                  // chunk5 landed; tail flying
  compute64<1, 0>(smem, qf, agg, d, l15, l4);
  BAR();

  stage_W(smem, wsW, wv, lane);                  // W bf16 (permuted) -> buf1
  asm volatile("s_waitcnt vmcnt(0)" ::: "memory");
  __syncthreads();   // full drain (tail + W)

  compute64<0, 1>(smem, qf, agg, d, l15, l4);    // tail (buf0)
  // everything below is per-wave; no more block barriers needed

  // denominator over the 4 l4-groups sharing pixel l15
  float inv[2];
  #pragma unroll
  for (int pt = 0; pt < 2; ++pt) {
    float s = d[pt];
    s += __shfl_xor(s, 16);
    s += __shfl_xor(s, 32);
    inv[pt] = 1.0f / s;
  }

  // conv: lane-local AGG B-fragments (wsW column-permuted to match)
  f32x4 cacc[8][2];
  #pragma unroll
  for (int ot = 0; ot < 8; ++ot) {
    cacc[ot][0] = (f32x4){0.f,0.f,0.f,0.f};
    cacc[ot][1] = (f32x4){0.f,0.f,0.f,0.f};
  }
  #pragma unroll
  for (int qh = 0; qh < 4; ++qh) {
    bf16x8 agf[2];
    #pragma unroll
    for (int pt = 0; pt < 2; ++pt) {
      bf16x8 t;
      #pragma unroll
      for (int j = 0; j < 8; ++j)
        t[j] = (short)f2bf(agg[2*qh + (j >> 2)][pt][j & 3] * inv[pt]);
      agf[pt] = t;
    }
    #pragma unroll
    for (int ot = 0; ot < 8; ++ot) {
      const bf16x8 wa = *(const bf16x8*)(smem + BUFSZ + (ot*16 + l15) * 256 +
                                         ((qh*64 + l4*16) ^ (l15 << 4)));
      cacc[ot][0] = MFMA32(wa, agf[0], cacc[ot][0], 0, 0, 0);
      cacc[ot][1] = MFMA32(wa, agf[1], cacc[ot][1], 0, 0, 0);
    }
  }

  // store: + bias + residual
  #pragma unroll
  for (int ot = 0; ot < 8; ++ot) {
    const float4 bq = *(const float4*)(b_out + ot*16 + l4*4);
    #pragma unroll
    for (int pt = 0; pt < 2; ++pt) {
      #pragma unroll
      for (int qi = 0; qi < 4; ++qi) {
        const int o = ot*16 + l4*4 + qi;
        const size_t idx = (((size_t)(b * C_N + o)) << 16) + pix0 + wv*32 + pt*16 + l15;
        out[idx] = cacc[ot][pt][qi] + ((const float*)&bq)[qi] + x5[idx];
      }
    }
  }
}

extern "C" void kernel_launch(void* const* d_in, const int* in_sizes, int n_in,
                              void* d_out, int out_size, void* d_ws, size_t ws_size,
                              hipStream_t stream) {
  const float* x5    = (const float*)d_in[0];
  const float* W_out = (const float*)d_in[1];
  const float* b_out = (const float*)d_in[2];
  float* out = (float*)d_out;
  // ws layout: wsKT first (tail staging overreads past rows; lands in wsK/wsW)
  u16* wsKT = (u16*)d_ws;                                        // [4][128][400] bf16
  u16* wsK  = (u16*)((char*)d_ws + (size_t)B_N * C_N * NKP * 2); // [4][400][128] bf16
  u16* wsW  = (u16*)((char*)d_ws + (size_t)2 * B_N * C_N * NKP * 2); // [128][128] bf16

  pool_kernel<<<512, 1024, 0, stream>>>(x5, W_out, wsK, wsKT, wsW, out);

  hipFuncSetAttribute((const void*)attn_kernel,
                      hipFuncAttributeMaxDynamicSharedMemorySize, LDS_BYTES);
  attn_kernel<<<B_N * 256, 512, LDS_BYTES, stream>>>(x5, wsK, wsKT, wsW, b_out, out);
}

// Round 19
// 515.978 us; speedup vs baseline: 1.1342x; 1.1342x over previous
//
#include <hip/hip_runtime.h>
#include <hip/hip_bf16.h>

typedef short bf16x8 __attribute__((ext_vector_type(8)));
typedef float f32x4  __attribute__((ext_vector_type(4)));
typedef unsigned short u16;

#define B_N 4
#define C_N 128
#define HW_ 256
#define NPIX 65536
#define NK 396
#define NKP 400
#define OUT_MAIN ((size_t)B_N * C_N * NPIX)
#define P12_OFF OUT_MAIN
#define P6_OFF  (P12_OFF + (size_t)B_N * C_N * 144)

// attn LDS arena: two 32KB buffers (K 16KB + VT 16KB each); no P region
#define BUFSZ  32768
#define VT_OFF 16384
#define LDS_BYTES 65536

static __device__ __forceinline__ u16 f2bf(float x) {
  __hip_bfloat16 h = __float2bfloat16(x);
  return *(u16*)&h;
}
static __device__ __forceinline__ unsigned pack2(float lo, float hi) {
  return ((unsigned)f2bf(hi) << 16) | f2bf(lo);
}
static __device__ __forceinline__ void gl_lds16(const void* g, void* l) {
  __builtin_amdgcn_global_load_lds(
      (const __attribute__((address_space(1))) unsigned*)g,
      (__attribute__((address_space(3))) unsigned*)l, 16, 0, 0);
}
#define MFMA32 __builtin_amdgcn_mfma_f32_16x16x32_bf16
#define BAR() do { __builtin_amdgcn_s_barrier(); \
                   __builtin_amdgcn_sched_barrier(0); } while (0)
#define VM8() do { asm volatile("s_waitcnt vmcnt(8)" ::: "memory"); \
                   __builtin_amdgcn_sched_barrier(0); } while (0)
#define VM4() do { asm volatile("s_waitcnt vmcnt(4)" ::: "memory"); \
                   __builtin_amdgcn_sched_barrier(0); } while (0)

// ---- pool Phase A body, H0 compile-time: all segment math constant-folds ----
template<int H0>
static __device__ __forceinline__ void pool_phaseA(
    const float2* __restrict__ plane2, float (*yh)[257], int w2)
{
  const int os_[7] = {16,12,9,7,6,3,1};
  const int ro_[7] = {0,16,28,37,44,50,53};
  float ax[7], ay[7], a2x[7], a2y[7], inv_[7];
  int r_[7], e_[7], s2_[7];
  #pragma unroll
  for (int s = 0; s < 7; ++s) {
    const int o = os_[s];
    const int r = (H0 * o) >> 8;
    const int sr = (r * 256) / o;
    r_[s]  = r;
    e_[s]  = ((r + 1) * 256 + o - 1) / o;
    s2_[s] = ((r + 1) * 256) / o;
    inv_[s] = 1.0f / (float)(e_[s] - sr);
    ax[s] = 0.f; ay[s] = 0.f; a2x[s] = 0.f; a2y[s] = 0.f;
  }
  #pragma unroll
  for (int g = 0; g < 4; ++g) {
    float2 vv[8];
    #pragma unroll
    for (int k = 0; k < 8; ++k) vv[k] = plane2[(H0 + g*8 + k) * 128 + w2];
    #pragma unroll
    for (int k = 0; k < 8; ++k) {
      const int h = H0 + g*8 + k;
      const float2 v = vv[k];
      #pragma unroll
      for (int s = 0; s < 7; ++s) {
        const int o = os_[s];
        ax[s] += v.x; ay[s] += v.y;
        if (h >= s2_[s]) { a2x[s] += v.x; a2y[s] += v.y; }
        if (h + 1 == e_[s]) {
          atomicAdd(&yh[ro_[s] + r_[s]][2*w2],     ax[s] * inv_[s]);
          atomicAdd(&yh[ro_[s] + r_[s]][2*w2 + 1], ay[s] * inv_[s]);
          r_[s]++;
          const int sr = s2_[s];
          e_[s]  = ((r_[s] + 1) * 256 + o - 1) / o;
          s2_[s] = ((r_[s] + 1) * 256) / o;
          inv_[s] = 1.0f / (float)(e_[s] - sr);
          ax[s] = a2x[s]; ay[s] = a2y[s];
          a2x[s] = 0.f; a2y[s] = 0.f;
        }
      }
    }
  }
  // flush in-progress segments (partials for segments crossing chunk end)
  #pragma unroll
  for (int s = 0; s < 7; ++s) {
    const int o = os_[s];
    if (r_[s] < o) {
      atomicAdd(&yh[ro_[s] + r_[s]][2*w2],     ax[s] * inv_[s]);
      atomicAdd(&yh[ro_[s] + r_[s]][2*w2 + 1], ay[s] * inv_[s]);
      if (r_[s] + 1 < o && s2_[s] < H0 + 32) {
        const int sr2 = s2_[s];
        const int e2  = ((r_[s] + 2) * 256 + o - 1) / o;
        const float inv2 = 1.0f / (float)(e2 - sr2);
        atomicAdd(&yh[ro_[s] + r_[s] + 1][2*w2],     a2x[s] * inv2);
        atomicAdd(&yh[ro_[s] + r_[s] + 1][2*w2 + 1], a2y[s] * inv2);
      }
    }
  }
}

// ---------------- kernel 1: multi-scale adaptive avg pools ----------------
__global__ __launch_bounds__(1024) void pool_kernel(
    const float* __restrict__ x5, const float* __restrict__ W_out,
    u16* __restrict__ wsK, u16* __restrict__ wsKT, u16* __restrict__ wsW,
    float* __restrict__ out)
{
  __shared__ float yh[54][257];
  const int tid = threadIdx.x;
  const int bc = blockIdx.x;          // b*128+c
  const int b  = bc >> 7;
  const int c  = bc & 127;
  const float2* plane2 = (const float2*)(x5 + (size_t)bc * NPIX);
  const int w2 = tid & 127;           // columns 2*w2, 2*w2+1
  const int q  = tid >> 7;            // row chunk 0..7 (wave-uniform)

  if (bc < 16) {                      // W f32 -> bf16, conv-fragment column perm
    const int idx = bc * 1024 + tid;
    const int o = idx >> 7, pp = idx & 127;
    const int q32 = pp >> 5, pos = pp & 31, g = pos >> 3, jj = pos & 7;
    const int csrc = q32 * 32 + ((jj < 4) ? (g * 4 + jj) : (16 + g * 4 + (jj - 4)));
    wsW[idx] = f2bf(W_out[o * 128 + csrc]);
  }

  // zero the accumulator tile
  for (int i = tid; i < 54 * 257; i += 1024) ((float*)yh)[i] = 0.f;
  __syncthreads();

  switch (q) {
    case 0: pool_phaseA<0>  (plane2, yh, w2); break;
    case 1: pool_phaseA<32> (plane2, yh, w2); break;
    case 2: pool_phaseA<64> (plane2, yh, w2); break;
    case 3: pool_phaseA<96> (plane2, yh, w2); break;
    case 4: pool_phaseA<128>(plane2, yh, w2); break;
    case 5: pool_phaseA<160>(plane2, yh, w2); break;
    case 6: pool_phaseA<192>(plane2, yh, w2); break;
    default: pool_phaseA<224>(plane2, yh, w2); break;
  }
  __syncthreads();

  // zero key-padding 396..399
  if (tid < NKP - NK) {
    wsK [((size_t)b * NKP + NK + tid) * C_N + c] = 0;
    wsKT[(size_t)bc * NKP + NK + tid] = 0;
  }

  // Phase B: 64 groups of 16 lanes; each group reduces one output per iter
  const int grp = tid >> 4;
  const int gl  = tid & 15;
  #pragma unroll
  for (int it = 0; it < 9; ++it) {
    const int r = grp + it * 64;
    int rr = r;
    int o, ro, kbase, dst;   // dst: 0=Key, 1=p12, 2=p6
    if      (rr < 256) { o = 16; ro = 0;  kbase = 140; dst = 0; }
    else if (rr < 400) { o = 12; ro = 16; kbase = 0;   dst = 1; rr -= 256; }
    else if (rr < 481) { o = 9;  ro = 28; kbase = 10;  dst = 0; rr -= 400; }
    else if (rr < 530) { o = 7;  ro = 37; kbase = 91;  dst = 0; rr -= 481; }
    else if (rr < 566) { o = 6;  ro = 44; kbase = 0;   dst = 2; rr -= 530; }
    else if (rr < 575) { o = 3;  ro = 50; kbase = 0;   dst = 0; rr -= 566; }
    else               { o = 1;  ro = 53; kbase = 9;   dst = 0; rr = 0;   }
    const int i = rr / o;
    const int j = rr - i * o;
    const int s = (j * HW_) / o;
    const int e = ((j + 1) * HW_ + o - 1) / o;
    float partial = 0.f;
    const float* row = yh[ro + i];
    for (int wq = s + gl; wq < e; wq += 16) partial += row[wq];
    partial += __shfl_xor(partial, 1);
    partial += __shfl_xor(partial, 2);
    partial += __shfl_xor(partial, 4);
    partial += __shfl_xor(partial, 8);
    if (gl == 0) {
      const float v = partial * (1.0f / (float)(e - s));
      if (dst == 1) {
        out[P12_OFF + (size_t)bc * 144 + rr] = v;
      } else if (dst == 2) {
        out[P6_OFF + (size_t)bc * 36 + rr] = v;
      } else {
        const int key = kbase + rr;
        const u16 bv = f2bf(v);
        wsK [((size_t)b * NKP + key) * C_N + c] = bv;   // [b][key][c]
        wsKT[(size_t)bc * NKP + key]            = bv;   // [b][c][key]
      }
    }
  }
}

// ---------------- attn staging helpers (256 threads = 4 waves) ------------
// K rows staged PERMUTED: tile j, row rit=4*wv+lr holds global key
// CB + (j>>1)*32 + 8*wv + (j&1)*4 + lr, so each lane's 8 scores across a
// tile pair are keys 8*l4..8*l4+7 (natural order) -> P is lane-local.
template<int CB, int BUF>
static __device__ __forceinline__ void stage64(
    char* smem, const char* wsKb, const char* wsKTb, int wv, int lane)
{
  char* buf = smem + BUF * BUFSZ;
  const int lr = lane >> 4, lc = lane & 15;
  const int rit = wv * 4 + lr;                            // dest row in tile
  #pragma unroll
  for (int j = 0; j < 4; ++j) {
    const int gk = CB + (j >> 1) * 32 + wv * 8 + ((j & 1) << 2) + lr;
    gl_lds16(wsKb + (size_t)gk * 256 + ((lc ^ rit) << 4),
             buf + j*4096 + wv*1024);
    const int vrow = j*32 + wv*8 + (lane >> 3);           // 128 c rows x 128B
    gl_lds16(wsKTb + (size_t)vrow * (NKP*2) + CB*2 + (((lane & 7) ^ (vrow & 7)) << 4),
             buf + VT_OFF + j*4096 + wv*1024);
  }
}

static __device__ __forceinline__ void stage_tail(
    char* buf, const char* wsKb, const char* wsKTb, int wv, int lane)
{
  const int lr = lane >> 4;
  const int rit = wv * 4 + lr;
  #pragma unroll
  for (int j = 0; j < 2; ++j) {  // K: 2 permuted tiles; keys >=396 zeroed/masked
    const int gk = 384 + wv * 8 + (j << 2) + lr;          // up to 415: in-ws garbage, masked
    gl_lds16(wsKb + (size_t)gk * 256 + (((lane & 15) ^ rit) << 4),
             buf + j*4096 + wv*1024);
  }
  #pragma unroll
  for (int j = 0; j < 2; ++j) {  // VT: 128 rows x 64B (32B real + 32B overread)
    const int row = j*64 + wv*16 + (lane >> 2);
    gl_lds16(wsKTb + (size_t)row * (NKP*2) + 768 + ((lane & 3) << 4),
             buf + VT_OFF + j*4096 + wv*1024);
  }
}

static __device__ __forceinline__ void stage_W(
    char* smem, const u16* wsW, int wv, int lane)
{
  #pragma unroll
  for (int j = 0; j < 8; ++j) {   // 128 rows x 256B bf16 -> buf1
    const int row = j*16 + wv*4 + (lane >> 4);
    gl_lds16((const char*)wsW + (size_t)row * 256 + (((lane & 15) ^ (row & 15)) << 4),
             smem + BUFSZ + j*4096 + wv*1024);
  }
}

// ------ per-64-key chunk: QK^T -> exp -> PV; P stays in registers --------
template<int BUF, int TAIL>
static __device__ __forceinline__ void compute64(
    char* smem, const bf16x8 (&qf)[2][4],
    f32x4 (&agg)[8][2], float (&d)[2], int l15, int l4)
{
  const char* buf = smem + BUF * BUFSZ;
  constexpr int NT   = TAIL ? 2 : 4;
  constexpr int SUBS = TAIL ? 1 : 2;

  f32x4 sA[NT][2];
  #pragma unroll
  for (int nt = 0; nt < NT; ++nt) {
    sA[nt][0] = (f32x4){0.f,0.f,0.f,0.f};
    sA[nt][1] = (f32x4){0.f,0.f,0.f,0.f};
  }
  #pragma unroll
  for (int nt = 0; nt < NT; ++nt) {
    bf16x8 kf[4];
    #pragma unroll
    for (int kc = 0; kc < 4; ++kc)
      kf[kc] = *(const bf16x8*)(buf + (nt*16 + l15) * 256 +
                                ((kc*64 + l4*16) ^ (l15 << 4)));
    #pragma unroll
    for (int kc = 0; kc < 4; ++kc) {
      sA[nt][0] = MFMA32(kf[kc], qf[0][kc], sA[nt][0], 0, 0, 0);
      sA[nt][1] = MFMA32(kf[kc], qf[1][kc], sA[nt][1], 0, 0, 0);
    }
  }

  #pragma unroll
  for (int sub = 0; sub < SUBS; ++sub) {
    bf16x8 pf[2];
    #pragma unroll
    for (int pt = 0; pt < 2; ++pt) {
      float e[8];
      #pragma unroll
      for (int qi = 0; qi < 4; ++qi) e[qi]     = exp2f(sA[2*sub][pt][qi]);
      #pragma unroll
      for (int qi = 0; qi < 4; ++qi) e[4 + qi] = exp2f(sA[2*sub + 1][pt][qi]);
      if (TAIL) {
        #pragma unroll
        for (int j = 0; j < 8; ++j) if (l4*8 + j >= 12) e[j] = 0.f;
      }
      d[pt] += ((e[0]+e[1]) + (e[2]+e[3])) + ((e[4]+e[5]) + (e[6]+e[7]));
      bf16x8 t;
      #pragma unroll
      for (int j = 0; j < 8; ++j) t[j] = (short)f2bf(e[j]);
      pf[pt] = t;
    }
    #pragma unroll
    for (int ct = 0; ct < 8; ++ct) {
      const int vrow = ct*16 + l15;
      bf16x8 vf;
      if (TAIL)
        vf = *(const bf16x8*)(buf + VT_OFF + vrow*64 + l4*16);
      else
        vf = *(const bf16x8*)(buf + VT_OFF + vrow*128 +
                              ((sub*64 + l4*16) ^ ((vrow & 7) << 4)));
      agg[ct][0] = MFMA32(vf, pf[0], agg[ct][0], 0, 0, 0);
      agg[ct][1] = MFMA32(vf, pf[1], agg[ct][1], 0, 0, 0);
    }
  }
}

// -------- kernel 2: MFMA attention + 1x1 conv + bias + residual --------
// Two 128-pixel tiles per block share each staged K/V chunk.
__global__ __launch_bounds__(256, 2) void attn_kernel(
    const float* __restrict__ x5, const u16* __restrict__ wsK,
    const u16* __restrict__ wsKT, const u16* __restrict__ wsW,
    const float* __restrict__ b_out, float* __restrict__ out)
{
  extern __shared__ char smem[];
  const int tid  = threadIdx.x;
  // bijective XCD swizzle: 1024 blocks, 8 XCDs, 128 contiguous per XCD
  const int wgid = (blockIdx.x & 7) * 128 + (blockIdx.x >> 3);
  const int b    = wgid >> 8;
  const int pix0 = (wgid & 255) << 8;           // 256 pixels per block
  const int lane = tid & 63, wv = tid >> 6;
  const int l15  = lane & 15, l4 = lane >> 4;
  const float SCL2 = 0.044194173824159216f * 1.4426950408889634f;

  const char* wsKb  = (const char*)wsK  + (size_t)b * NKP * C_N * 2;
  const char* wsKTb = (const char*)wsKT + (size_t)b * C_N * NKP * 2;

  // ---- stage Q tiles A and B (scale folded in), fragments -> registers ----
  bf16x8 qfA[2][4], qfB[2][4];
  #pragma unroll
  for (int tile = 0; tile < 2; ++tile) {
    const float* r0p = x5 + (((size_t)(b * C_N + 2*lane)) << 16) + pix0 +
                       tile * 128 + wv * 32;
    const float* r1p = r0p + NPIX;
    float4 v0[8], v1[8];
    #pragma unroll
    for (int j = 0; j < 8; ++j) {
      v0[j] = *(const float4*)(r0p + j*4);
      v1[j] = *(const float4*)(r1p + j*4);
    }
    #pragma unroll
    for (int i = 0; i < 32; ++i) {
      const int pix = wv * 32 + i;
      const unsigned pk = pack2(((const float*)&v0[i>>2])[i&3] * SCL2,
                                ((const float*)&v1[i>>2])[i&3] * SCL2);
      *(unsigned*)(smem + pix * 256 + ((lane*4) ^ ((pix & 15) << 4))) = pk;
    }
    __syncthreads();
    #pragma unroll
    for (int pt = 0; pt < 2; ++pt)
      #pragma unroll
      for (int kc = 0; kc < 4; ++kc) {
        const bf16x8 v = *(const bf16x8*)(smem + (wv*32 + pt*16 + l15) * 256 +
                                          ((kc*64 + l4*16) ^ (l15 << 4)));
        if (tile == 0) qfA[pt][kc] = v; else qfB[pt][kc] = v;
      }
    __syncthreads();
  }

  f32x4 aggA[8][2], aggB[8][2];
  #pragma unroll
  for (int ct = 0; ct < 8; ++ct) {
    aggA[ct][0] = (f32x4){0.f,0.f,0.f,0.f};
    aggA[ct][1] = (f32x4){0.f,0.f,0.f,0.f};
    aggB[ct][0] = (f32x4){0.f,0.f,0.f,0.f};
    aggB[ct][1] = (f32x4){0.f,0.f,0.f,0.f};
  }
  float dA[2] = {0.f, 0.f}, dB[2] = {0.f, 0.f};

  // ---- chunk pipeline: counted vmcnt keeps next-chunk loads in flight ----
  stage64<0, 0>(smem, wsKb, wsKTb, wv, lane);
  stage64<64, 1>(smem, wsKb, wsKTb, wv, lane);
  VM8(); BAR();                                  // chunk0 landed; chunk1 flying
  compute64<0, 0>(smem, qfA, aggA, dA, l15, l4);
  compute64<0, 0>(smem, qfB, aggB, dB, l15, l4);
  BAR();                                         // all waves done reading buf0

  stage64<128, 0>(smem, wsKb, wsKTb, wv, lane);
  VM8(); BAR();
  compute64<1, 0>(smem, qfA, aggA, dA, l15, l4);
  compute64<1, 0>(smem, qfB, aggB, dB, l15, l4);
  BAR();

  stage64<192, 1>(smem, wsKb, wsKTb, wv, lane);
  VM8(); BAR();
  compute64<0, 0>(smem, qfA, aggA, dA, l15, l4);
  compute64<0, 0>(smem, qfB, aggB, dB, l15, l4);
  BAR();

  stage64<256, 0>(smem, wsKb, wsKTb, wv, lane);
  VM8(); BAR();
  compute64<1, 0>(smem, qfA, aggA, dA, l15, l4);
  compute64<1, 0>(smem, qfB, aggB, dB, l15, l4);
  BAR();

  stage64<320, 1>(smem, wsKb, wsKTb, wv, lane);
  VM8(); BAR();
  compute64<0, 0>(smem, qfA, aggA, dA, l15, l4);
  compute64<0, 0>(smem, qfB, aggB, dB, l15, l4);
  BAR();

  stage_tail(smem, wsKb, wsKTb, wv, lane);       // tail -> buf0 (4 loads/wave)
  VM4(); BAR();                                  // chunk5 landed; tail flying
  compute64<1, 0>(smem, qfA, aggA, dA, l15, l4);
  compute64<1, 0>(smem, qfB, aggB, dB, l15, l4);
  BAR();

  stage_W(smem, wsW, wv, lane);                  // W bf16 (permuted) -> buf1
  asm volatile("s_waitcnt vmcnt(0)" ::: "memory");
  __syncthreads();   // full drain (tail + W)

  compute64<0, 1>(smem, qfA, aggA, dA, l15, l4); // tail (buf0)
  compute64<0, 1>(smem, qfB, aggB, dB, l15, l4);
  // everything below is per-wave; no more block barriers needed

  // denominators
  float invA[2], invB[2];
  #pragma unroll
  for (int pt = 0; pt < 2; ++pt) {
    float s = dA[pt];
    s += __shfl_xor(s, 16);
    s += __shfl_xor(s, 32);
    invA[pt] = 1.0f / s;
    float s2 = dB[pt];
    s2 += __shfl_xor(s2, 16);
    s2 += __shfl_xor(s2, 32);
    invB[pt] = 1.0f / s2;
  }

  // conv per tile: lane-local AGG B-fragments (wsW column-permuted to match)
  #pragma unroll
  for (int tile = 0; tile < 2; ++tile) {
    f32x4 cacc[8][2];
    #pragma unroll
    for (int ot = 0; ot < 8; ++ot) {
      cacc[ot][0] = (f32x4){0.f,0.f,0.f,0.f};
      cacc[ot][1] = (f32x4){0.f,0.f,0.f,0.f};
    }
    #pragma unroll
    for (int qh = 0; qh < 4; ++qh) {
      bf16x8 agf[2];
      #pragma unroll
      for (int pt = 0; pt < 2; ++pt) {
        bf16x8 t;
        #pragma unroll
        for (int j = 0; j < 8; ++j) {
          const float a = tile ? aggB[2*qh + (j >> 2)][pt][j & 3] * invB[pt]
                               : aggA[2*qh + (j >> 2)][pt][j & 3] * invA[pt];
          t[j] = (short)f2bf(a);
        }
        agf[pt] = t;
      }
      #pragma unroll
      for (int ot = 0; ot < 8; ++ot) {
        const bf16x8 wa = *(const bf16x8*)(smem + BUFSZ + (ot*16 + l15) * 256 +
                                           ((qh*64 + l4*16) ^ (l15 << 4)));
        cacc[ot][0] = MFMA32(wa, agf[0], cacc[ot][0], 0, 0, 0);
        cacc[ot][1] = MFMA32(wa, agf[1], cacc[ot][1], 0, 0, 0);
      }
    }
    // store: + bias + residual
    #pragma unroll
    for (int ot = 0; ot < 8; ++ot) {
      const float4 bq = *(const float4*)(b_out + ot*16 + l4*4);
      #pragma unroll
      for (int pt = 0; pt < 2; ++pt) {
        #pragma unroll
        for (int qi = 0; qi < 4; ++qi) {
          const int o = ot*16 + l4*4 + qi;
          const size_t idx = (((size_t)(b * C_N + o)) << 16) + pix0 +
                             tile * 128 + wv*32 + pt*16 + l15;
          out[idx] = cacc[ot][pt][qi] + ((const float*)&bq)[qi] + x5[idx];
        }
      }
    }
  }
}

extern "C" void kernel_launch(void* const* d_in, const int* in_sizes, int n_in,
                              void* d_out, int out_size, void* d_ws, size_t ws_size,
                              hipStream_t stream) {
  const float* x5    = (const float*)d_in[0];
  const float* W_out = (const float*)d_in[1];
  const float* b_out = (const float*)d_in[2];
  float* out = (float*)d_out;
  // ws layout: wsKT first (tail staging overreads past rows; lands in wsK/wsW)
  u16* wsKT = (u16*)d_ws;                                        // [4][128][400] bf16
  u16* wsK  = (u16*)((char*)d_ws + (size_t)B_N * C_N * NKP * 2); // [4][400][128] bf16
  u16* wsW  = (u16*)((char*)d_ws + (size_t)2 * B_N * C_N * NKP * 2); // [128][128] bf16

  pool_kernel<<<512, 1024, 0, stream>>>(x5, W_out, wsK, wsKT, wsW, out);

  hipFuncSetAttribute((const void*)attn_kernel,
                      hipFuncAttributeMaxDynamicSharedMemorySize, LDS_BYTES);
  attn_kernel<<<B_N * 256, 256, LDS_BYTES, stream>>>(x5, wsK, wsKT, wsW, b_out, out);
}

// Round 20
// 186.086 us; speedup vs baseline: 3.1449x; 2.7728x over previous
//
#include <hip/hip_runtime.h>
#include <hip/hip_bf16.h>

typedef short bf16x8 __attribute__((ext_vector_type(8)));
typedef float f32x4  __attribute__((ext_vector_type(4)));
typedef unsigned short u16;

#define B_N 4
#define C_N 128
#define HW_ 256
#define NPIX 65536
#define NK 396
#define NKP 400
#define OUT_MAIN ((size_t)B_N * C_N * NPIX)
#define P12_OFF OUT_MAIN
#define P6_OFF  (P12_OFF + (size_t)B_N * C_N * 144)

// attn LDS arena: two 32KB buffers (K 16KB + VT 16KB each); no P region
#define BUFSZ  32768
#define VT_OFF 16384
#define LDS_BYTES 65536

static __device__ __forceinline__ u16 f2bf(float x) {
  __hip_bfloat16 h = __float2bfloat16(x);
  return *(u16*)&h;
}
static __device__ __forceinline__ unsigned pack2(float lo, float hi) {
  return ((unsigned)f2bf(hi) << 16) | f2bf(lo);
}
static __device__ __forceinline__ void gl_lds16(const void* g, void* l) {
  __builtin_amdgcn_global_load_lds(
      (const __attribute__((address_space(1))) unsigned*)g,
      (__attribute__((address_space(3))) unsigned*)l, 16, 0, 0);
}
#define MFMA32 __builtin_amdgcn_mfma_f32_16x16x32_bf16
#define BAR() do { __builtin_amdgcn_s_barrier(); \
                   __builtin_amdgcn_sched_barrier(0); } while (0)
#define VM8() do { asm volatile("s_waitcnt vmcnt(8)" ::: "memory"); \
                   __builtin_amdgcn_sched_barrier(0); } while (0)
#define VM4() do { asm volatile("s_waitcnt vmcnt(4)" ::: "memory"); \
                   __builtin_amdgcn_sched_barrier(0); } while (0)

// ---- pool Phase A body, H0 compile-time: all segment math constant-folds ----
template<int H0>
static __device__ __forceinline__ void pool_phaseA(
    const float2* __restrict__ plane2, float (*yh)[257], int w2)
{
  const int os_[7] = {16,12,9,7,6,3,1};
  const int ro_[7] = {0,16,28,37,44,50,53};
  float ax[7], ay[7], a2x[7], a2y[7], inv_[7];
  int r_[7], e_[7], s2_[7];
  #pragma unroll
  for (int s = 0; s < 7; ++s) {
    const int o = os_[s];
    const int r = (H0 * o) >> 8;
    const int sr = (r * 256) / o;
    r_[s]  = r;
    e_[s]  = ((r + 1) * 256 + o - 1) / o;
    s2_[s] = ((r + 1) * 256) / o;
    inv_[s] = 1.0f / (float)(e_[s] - sr);
    ax[s] = 0.f; ay[s] = 0.f; a2x[s] = 0.f; a2y[s] = 0.f;
  }
  #pragma unroll
  for (int g = 0; g < 4; ++g) {
    float2 vv[8];
    #pragma unroll
    for (int k = 0; k < 8; ++k) vv[k] = plane2[(H0 + g*8 + k) * 128 + w2];
    #pragma unroll
    for (int k = 0; k < 8; ++k) {
      const int h = H0 + g*8 + k;
      const float2 v = vv[k];
      #pragma unroll
      for (int s = 0; s < 7; ++s) {
        const int o = os_[s];
        ax[s] += v.x; ay[s] += v.y;
        if (h >= s2_[s]) { a2x[s] += v.x; a2y[s] += v.y; }
        if (h + 1 == e_[s]) {
          atomicAdd(&yh[ro_[s] + r_[s]][2*w2],     ax[s] * inv_[s]);
          atomicAdd(&yh[ro_[s] + r_[s]][2*w2 + 1], ay[s] * inv_[s]);
          r_[s]++;
          const int sr = s2_[s];
          e_[s]  = ((r_[s] + 1) * 256 + o - 1) / o;
          s2_[s] = ((r_[s] + 1) * 256) / o;
          inv_[s] = 1.0f / (float)(e_[s] - sr);
          ax[s] = a2x[s]; ay[s] = a2y[s];
          a2x[s] = 0.f; a2y[s] = 0.f;
        }
      }
    }
  }
  // flush in-progress segments (partials for segments crossing chunk end)
  #pragma unroll
  for (int s = 0; s < 7; ++s) {
    const int o = os_[s];
    if (r_[s] < o) {
      atomicAdd(&yh[ro_[s] + r_[s]][2*w2],     ax[s] * inv_[s]);
      atomicAdd(&yh[ro_[s] + r_[s]][2*w2 + 1], ay[s] * inv_[s]);
      if (r_[s] + 1 < o && s2_[s] < H0 + 32) {
        const int sr2 = s2_[s];
        const int e2  = ((r_[s] + 2) * 256 + o - 1) / o;
        const float inv2 = 1.0f / (float)(e2 - sr2);
        atomicAdd(&yh[ro_[s] + r_[s] + 1][2*w2],     a2x[s] * inv2);
        atomicAdd(&yh[ro_[s] + r_[s] + 1][2*w2 + 1], a2y[s] * inv2);
      }
    }
  }
}

// ---------------- kernel 1: multi-scale adaptive avg pools ----------------
__global__ __launch_bounds__(1024) void pool_kernel(
    const float* __restrict__ x5, const float* __restrict__ W_out,
    u16* __restrict__ wsK, u16* __restrict__ wsKT, u16* __restrict__ wsW,
    float* __restrict__ out)
{
  __shared__ float yh[54][257];
  const int tid = threadIdx.x;
  const int bc = blockIdx.x;          // b*128+c
  const int b  = bc >> 7;
  const int c  = bc & 127;
  const float2* plane2 = (const float2*)(x5 + (size_t)bc * NPIX);
  const int w2 = tid & 127;           // columns 2*w2, 2*w2+1
  const int q  = tid >> 7;            // row chunk 0..7 (wave-uniform)

  if (bc < 16) {                      // W f32 -> bf16, conv-fragment column perm
    const int idx = bc * 1024 + tid;
    const int o = idx >> 7, pp = idx & 127;
    const int q32 = pp >> 5, pos = pp & 31, g = pos >> 3, jj = pos & 7;
    const int csrc = q32 * 32 + ((jj < 4) ? (g * 4 + jj) : (16 + g * 4 + (jj - 4)));
    wsW[idx] = f2bf(W_out[o * 128 + csrc]);
  }

  // zero the accumulator tile
  for (int i = tid; i < 54 * 257; i += 1024) ((float*)yh)[i] = 0.f;
  __syncthreads();

  switch (q) {
    case 0: pool_phaseA<0>  (plane2, yh, w2); break;
    case 1: pool_phaseA<32> (plane2, yh, w2); break;
    case 2: pool_phaseA<64> (plane2, yh, w2); break;
    case 3: pool_phaseA<96> (plane2, yh, w2); break;
    case 4: pool_phaseA<128>(plane2, yh, w2); break;
    case 5: pool_phaseA<160>(plane2, yh, w2); break;
    case 6: pool_phaseA<192>(plane2, yh, w2); break;
    default: pool_phaseA<224>(plane2, yh, w2); break;
  }
  __syncthreads();

  // zero key-padding 396..399
  if (tid < NKP - NK) {
    wsK [((size_t)b * NKP + NK + tid) * C_N + c] = 0;
    wsKT[(size_t)bc * NKP + NK + tid] = 0;
  }

  // Phase B: 64 groups of 16 lanes; each group reduces one output per iter
  const int grp = tid >> 4;
  const int gl  = tid & 15;
  #pragma unroll
  for (int it = 0; it < 9; ++it) {
    const int r = grp + it * 64;
    int rr = r;
    int o, ro, kbase, dst;   // dst: 0=Key, 1=p12, 2=p6
    if      (rr < 256) { o = 16; ro = 0;  kbase = 140; dst = 0; }
    else if (rr < 400) { o = 12; ro = 16; kbase = 0;   dst = 1; rr -= 256; }
    else if (rr < 481) { o = 9;  ro = 28; kbase = 10;  dst = 0; rr -= 400; }
    else if (rr < 530) { o = 7;  ro = 37; kbase = 91;  dst = 0; rr -= 481; }
    else if (rr < 566) { o = 6;  ro = 44; kbase = 0;   dst = 2; rr -= 530; }
    else if (rr < 575) { o = 3;  ro = 50; kbase = 0;   dst = 0; rr -= 566; }
    else               { o = 1;  ro = 53; kbase = 9;   dst = 0; rr = 0;   }
    const int i = rr / o;
    const int j = rr - i * o;
    const int s = (j * HW_) / o;
    const int e = ((j + 1) * HW_ + o - 1) / o;
    float partial = 0.f;
    const float* row = yh[ro + i];
    for (int wq = s + gl; wq < e; wq += 16) partial += row[wq];
    partial += __shfl_xor(partial, 1);
    partial += __shfl_xor(partial, 2);
    partial += __shfl_xor(partial, 4);
    partial += __shfl_xor(partial, 8);
    if (gl == 0) {
      const float v = partial * (1.0f / (float)(e - s));
      if (dst == 1) {
        out[P12_OFF + (size_t)bc * 144 + rr] = v;
      } else if (dst == 2) {
        out[P6_OFF + (size_t)bc * 36 + rr] = v;
      } else {
        const int key = kbase + rr;
        const u16 bv = f2bf(v);
        wsK [((size_t)b * NKP + key) * C_N + c] = bv;   // [b][key][c]
        wsKT[(size_t)bc * NKP + key]            = bv;   // [b][c][key]
      }
    }
  }
}

// ---------------- attn staging helpers (256 threads = 4 waves) ------------
// K rows staged PERMUTED: tile j, row rit=4*wv+lr holds global key
// CB + (j>>1)*32 + 8*wv + (j&1)*4 + lr, so each lane's 8 scores across a
// tile pair are keys 8*l4..8*l4+7 (natural order) -> P is lane-local.
template<int CB, int BUF>
static __device__ __forceinline__ void stage64(
    char* smem, const char* wsKb, const char* wsKTb, int wv, int lane)
{
  char* buf = smem + BUF * BUFSZ;
  const int lr = lane >> 4, lc = lane & 15;
  const int rit = wv * 4 + lr;                            // dest row in tile
  #pragma unroll
  for (int j = 0; j < 4; ++j) {
    const int gk = CB + (j >> 1) * 32 + wv * 8 + ((j & 1) << 2) + lr;
    gl_lds16(wsKb + (size_t)gk * 256 + ((lc ^ rit) << 4),
             buf + j*4096 + wv*1024);
    const int vrow = j*32 + wv*8 + (lane >> 3);           // 128 c rows x 128B
    gl_lds16(wsKTb + (size_t)vrow * (NKP*2) + CB*2 + (((lane & 7) ^ (vrow & 7)) << 4),
             buf + VT_OFF + j*4096 + wv*1024);
  }
}

static __device__ __forceinline__ void stage_tail(
    char* buf, const char* wsKb, const char* wsKTb, int wv, int lane)
{
  const int lr = lane >> 4;
  const int rit = wv * 4 + lr;
  #pragma unroll
  for (int j = 0; j < 2; ++j) {  // K: 2 permuted tiles; keys >=396 zeroed/masked
    const int gk = 384 + wv * 8 + (j << 2) + lr;          // up to 415: in-ws garbage, masked
    gl_lds16(wsKb + (size_t)gk * 256 + (((lane & 15) ^ rit) << 4),
             buf + j*4096 + wv*1024);
  }
  #pragma unroll
  for (int j = 0; j < 2; ++j) {  // VT: 128 rows x 64B (32B real + 32B overread)
    const int row = j*64 + wv*16 + (lane >> 2);
    gl_lds16(wsKTb + (size_t)row * (NKP*2) + 768 + ((lane & 3) << 4),
             buf + VT_OFF + j*4096 + wv*1024);
  }
}

static __device__ __forceinline__ void stage_W(
    char* smem, const u16* wsW, int wv, int lane)
{
  #pragma unroll
  for (int j = 0; j < 8; ++j) {   // 128 rows x 256B bf16 -> buf1
    const int row = j*16 + wv*4 + (lane >> 4);
    gl_lds16((const char*)wsW + (size_t)row * 256 + (((lane & 15) ^ (row & 15)) << 4),
             smem + BUFSZ + j*4096 + wv*1024);
  }
}

// ------ per-64-key chunk: QK^T -> exp -> PV; P stays in registers --------
template<int BUF, int TAIL>
static __device__ __forceinline__ void compute64(
    char* smem, const bf16x8 (&qf)[2][4],
    f32x4 (&agg)[8][2], float (&d)[2], int l15, int l4)
{
  const char* buf = smem + BUF * BUFSZ;
  constexpr int NT   = TAIL ? 2 : 4;
  constexpr int SUBS = TAIL ? 1 : 2;

  f32x4 sA[NT][2];
  #pragma unroll
  for (int nt = 0; nt < NT; ++nt) {
    sA[nt][0] = (f32x4){0.f,0.f,0.f,0.f};
    sA[nt][1] = (f32x4){0.f,0.f,0.f,0.f};
  }
  __builtin_amdgcn_s_setprio(1);
  #pragma unroll
  for (int nt = 0; nt < NT; ++nt) {
    bf16x8 kf[4];
    #pragma unroll
    for (int kc = 0; kc < 4; ++kc)
      kf[kc] = *(const bf16x8*)(buf + (nt*16 + l15) * 256 +
                                ((kc*64 + l4*16) ^ (l15 << 4)));
    #pragma unroll
    for (int kc = 0; kc < 4; ++kc) {
      sA[nt][0] = MFMA32(kf[kc], qf[0][kc], sA[nt][0], 0, 0, 0);
      sA[nt][1] = MFMA32(kf[kc], qf[1][kc], sA[nt][1], 0, 0, 0);
    }
  }
  __builtin_amdgcn_s_setprio(0);

  #pragma unroll
  for (int sub = 0; sub < SUBS; ++sub) {
    bf16x8 pf[2];
    #pragma unroll
    for (int pt = 0; pt < 2; ++pt) {
      float e[8];
      #pragma unroll
      for (int qi = 0; qi < 4; ++qi) e[qi]     = exp2f(sA[2*sub][pt][qi]);
      #pragma unroll
      for (int qi = 0; qi < 4; ++qi) e[4 + qi] = exp2f(sA[2*sub + 1][pt][qi]);
      if (TAIL) {
        #pragma unroll
        for (int j = 0; j < 8; ++j) if (l4*8 + j >= 12) e[j] = 0.f;
      }
      d[pt] += ((e[0]+e[1]) + (e[2]+e[3])) + ((e[4]+e[5]) + (e[6]+e[7]));
      bf16x8 t;
      #pragma unroll
      for (int j = 0; j < 8; ++j) t[j] = (short)f2bf(e[j]);
      pf[pt] = t;
    }
    __builtin_amdgcn_s_setprio(1);
    #pragma unroll
    for (int ct = 0; ct < 8; ++ct) {
      const int vrow = ct*16 + l15;
      bf16x8 vf;
      if (TAIL)
        vf = *(const bf16x8*)(buf + VT_OFF + vrow*64 + l4*16);
      else
        vf = *(const bf16x8*)(buf + VT_OFF + vrow*128 +
                              ((sub*64 + l4*16) ^ ((vrow & 7) << 4)));
      agg[ct][0] = MFMA32(vf, pf[0], agg[ct][0], 0, 0, 0);
      agg[ct][1] = MFMA32(vf, pf[1], agg[ct][1], 0, 0, 0);
    }
    __builtin_amdgcn_s_setprio(0);
  }
}

// -------- kernel 2: MFMA attention + 1x1 conv + bias + residual --------
__global__ __launch_bounds__(256, 2) void attn_kernel(
    const float* __restrict__ x5, const u16* __restrict__ wsK,
    const u16* __restrict__ wsKT, const u16* __restrict__ wsW,
    const float* __restrict__ b_out, float* __restrict__ out)
{
  extern __shared__ char smem[];
  const int tid  = threadIdx.x;
  // bijective XCD swizzle: 2048 blocks, 8 XCDs, 256 contiguous per XCD
  const int wgid = (blockIdx.x & 7) * 256 + (blockIdx.x >> 3);
  const int b    = wgid >> 9;
  const int pix0 = (wgid & 511) << 7;
  const int lane = tid & 63, wv = tid >> 6;
  const int l15  = lane & 15, l4 = lane >> 4;
  const float SCL2 = 0.044194173824159216f * 1.4426950408889634f;

  const char* wsKb  = (const char*)wsK  + (size_t)b * NKP * C_N * 2;
  const char* wsKTb = (const char*)wsKT + (size_t)b * C_N * NKP * 2;

  // ---- stage Q [128 pix][128 c] bf16 into buf0 (scale folded in) ----
  {
    const float* r0p = x5 + (((size_t)(b * C_N + 2*lane)) << 16) + pix0 + wv * 32;
    const float* r1p = r0p + NPIX;
    float4 v0[8], v1[8];
    #pragma unroll
    for (int j = 0; j < 8; ++j) {
      v0[j] = *(const float4*)(r0p + j*4);
      v1[j] = *(const float4*)(r1p + j*4);
    }
    #pragma unroll
    for (int i = 0; i < 32; ++i) {
      const int pix = wv * 32 + i;
      const unsigned pk = pack2(((const float*)&v0[i>>2])[i&3] * SCL2,
                                ((const float*)&v1[i>>2])[i&3] * SCL2);
      *(unsigned*)(smem + pix * 256 + ((lane*4) ^ ((pix & 15) << 4))) = pk;
    }
  }
  __syncthreads();

  bf16x8 qf[2][4];
  #pragma unroll
  for (int pt = 0; pt < 2; ++pt)
    #pragma unroll
    for (int kc = 0; kc < 4; ++kc)
      qf[pt][kc] = *(const bf16x8*)(smem + (wv*32 + pt*16 + l15) * 256 +
                                    ((kc*64 + l4*16) ^ (l15 << 4)));
  __syncthreads();

  f32x4 agg[8][2];
  #pragma unroll
  for (int ct = 0; ct < 8; ++ct) {
    agg[ct][0] = (f32x4){0.f,0.f,0.f,0.f};
    agg[ct][1] = (f32x4){0.f,0.f,0.f,0.f};
  }
  float d[2] = {0.f, 0.f};

  // ---- chunk pipeline: counted vmcnt keeps next-chunk loads in flight ----
  stage64<0, 0>(smem, wsKb, wsKTb, wv, lane);
  stage64<64, 1>(smem, wsKb, wsKTb, wv, lane);
  VM8(); BAR();                                  // chunk0 landed; chunk1 flying
  compute64<0, 0>(smem, qf, agg, d, l15, l4);
  BAR();                                         // all waves done reading buf0

  stage64<128, 0>(smem, wsKb, wsKTb, wv, lane);
  VM8(); BAR();
  compute64<1, 0>(smem, qf, agg, d, l15, l4);
  BAR();

  stage64<192, 1>(smem, wsKb, wsKTb, wv, lane);
  VM8(); BAR();
  compute64<0, 0>(smem, qf, agg, d, l15, l4);
  BAR();

  stage64<256, 0>(smem, wsKb, wsKTb, wv, lane);
  VM8(); BAR();
  compute64<1, 0>(smem, qf, agg, d, l15, l4);
  BAR();

  stage64<320, 1>(smem, wsKb, wsKTb, wv, lane);
  VM8(); BAR();
  compute64<0, 0>(smem, qf, agg, d, l15, l4);
  BAR();

  stage_tail(smem, wsKb, wsKTb, wv, lane);       // tail -> buf0 (4 loads/wave)
  VM4(); BAR();                                  // chunk5 landed; tail flying
  compute64<1, 0>(smem, qf, agg, d, l15, l4);
  BAR();

  stage_W(smem, wsW, wv, lane);                  // W bf16 (permuted) -> buf1
  asm volatile("s_waitcnt vmcnt(0)" ::: "memory");
  __syncthreads();   // full drain (tail + W)

  compute64<0, 1>(smem, qf, agg, d, l15, l4);    // tail (buf0)
  // everything below is per-wave; no more block barriers needed

  // denominator over the 4 l4-groups sharing pixel l15
  float inv[2];
  #pragma unroll
  for (int pt = 0; pt < 2; ++pt) {
    float s = d[pt];
    s += __shfl_xor(s, 16);
    s += __shfl_xor(s, 32);
    inv[pt] = 1.0f / s;
  }

  // conv: lane-local AGG B-fragments (wsW column-permuted to match)
  f32x4 cacc[8][2];
  #pragma unroll
  for (int ot = 0; ot < 8; ++ot) {
    cacc[ot][0] = (f32x4){0.f,0.f,0.f,0.f};
    cacc[ot][1] = (f32x4){0.f,0.f,0.f,0.f};
  }
  #pragma unroll
  for (int qh = 0; qh < 4; ++qh) {
    bf16x8 agf[2];
    #pragma unroll
    for (int pt = 0; pt < 2; ++pt) {
      bf16x8 t;
      #pragma unroll
      for (int j = 0; j < 8; ++j)
        t[j] = (short)f2bf(agg[2*qh + (j >> 2)][pt][j & 3] * inv[pt]);
      agf[pt] = t;
    }
    __builtin_amdgcn_s_setprio(1);
    #pragma unroll
    for (int ot = 0; ot < 8; ++ot) {
      const bf16x8 wa = *(const bf16x8*)(smem + BUFSZ + (ot*16 + l15) * 256 +
                                         ((qh*64 + l4*16) ^ (l15 << 4)));
      cacc[ot][0] = MFMA32(wa, agf[0], cacc[ot][0], 0, 0, 0);
      cacc[ot][1] = MFMA32(wa, agf[1], cacc[ot][1], 0, 0, 0);
    }
    __builtin_amdgcn_s_setprio(0);
  }

  // store: + bias + residual
  #pragma unroll
  for (int ot = 0; ot < 8; ++ot) {
    const float4 bq = *(const float4*)(b_out + ot*16 + l4*4);
    #pragma unroll
    for (int pt = 0; pt < 2; ++pt) {
      #pragma unroll
      for (int qi = 0; qi < 4; ++qi) {
        const int o = ot*16 + l4*4 + qi;
        const size_t idx = (((size_t)(b * C_N + o)) << 16) + pix0 + wv*32 + pt*16 + l15;
        out[idx] = cacc[ot][pt][qi] + ((const float*)&bq)[qi] + x5[idx];
      }
    }
  }
}

extern "C" void kernel_launch(void* const* d_in, const int* in_sizes, int n_in,
                              void* d_out, int out_size, void* d_ws, size_t ws_size,
                              hipStream_t stream) {
  const float* x5    = (const float*)d_in[0];
  const float* W_out = (const float*)d_in[1];
  const float* b_out = (const float*)d_in[2];
  float* out = (float*)d_out;
  // ws layout: wsKT first (tail staging overreads past rows; lands in wsK/wsW)
  u16* wsKT = (u16*)d_ws;                                        // [4][128][400] bf16
  u16* wsK  = (u16*)((char*)d_ws + (size_t)B_N * C_N * NKP * 2); // [4][400][128] bf16
  u16* wsW  = (u16*)((char*)d_ws + (size_t)2 * B_N * C_N * NKP * 2); // [128][128] bf16

  pool_kernel<<<512, 1024, 0, stream>>>(x5, W_out, wsK, wsKT, wsW, out);

  hipFuncSetAttribute((const void*)attn_kernel,
                      hipFuncAttributeMaxDynamicSharedMemorySize, LDS_BYTES);
  attn_kernel<<<B_N * 512, 256, LDS_BYTES, stream>>>(x5, wsK, wsKT, wsW, b_out, out);
}

// Round 21
// 181.823 us; speedup vs baseline: 3.2187x; 1.0234x over previous
//
#include <hip/hip_runtime.h>
#include <hip/hip_bf16.h>

typedef short bf16x8 __attribute__((ext_vector_type(8)));
typedef float f32x4  __attribute__((ext_vector_type(4)));
typedef unsigned short u16;

#define B_N 4
#define C_N 128
#define HW_ 256
#define NPIX 65536
#define NK 396
#define NKP 400
#define OUT_MAIN ((size_t)B_N * C_N * NPIX)
#define P12_OFF OUT_MAIN
#define P6_OFF  (P12_OFF + (size_t)B_N * C_N * 144)

// attn LDS arena: two 32KB buffers (K 16KB + VT 16KB each); no P region
#define BUFSZ  32768
#define VT_OFF 16384
#define LDS_BYTES 65536

static __device__ __forceinline__ u16 f2bf(float x) {
  __hip_bfloat16 h = __float2bfloat16(x);
  return *(u16*)&h;
}
static __device__ __forceinline__ unsigned pack2(float lo, float hi) {
  return ((unsigned)f2bf(hi) << 16) | f2bf(lo);
}
static __device__ __forceinline__ void gl_lds16(const void* g, void* l) {
  __builtin_amdgcn_global_load_lds(
      (const __attribute__((address_space(1))) unsigned*)g,
      (__attribute__((address_space(3))) unsigned*)l, 16, 0, 0);
}
#define MFMA32 __builtin_amdgcn_mfma_f32_16x16x32_bf16
#define BAR() do { __builtin_amdgcn_s_barrier(); \
                   __builtin_amdgcn_sched_barrier(0); } while (0)
#define VM8() do { asm volatile("s_waitcnt vmcnt(8)" ::: "memory"); \
                   __builtin_amdgcn_sched_barrier(0); } while (0)
#define VM4() do { asm volatile("s_waitcnt vmcnt(4)" ::: "memory"); \
                   __builtin_amdgcn_sched_barrier(0); } while (0)

// ---- pool Phase A body, H0 compile-time: all segment math constant-folds ----
template<int H0>
static __device__ __forceinline__ void pool_phaseA(
    const float2* __restrict__ plane2, float (*yh)[257], int w2)
{
  const int os_[7] = {16,12,9,7,6,3,1};
  const int ro_[7] = {0,16,28,37,44,50,53};
  float ax[7], ay[7], a2x[7], a2y[7], inv_[7];
  int r_[7], e_[7], s2_[7];
  #pragma unroll
  for (int s = 0; s < 7; ++s) {
    const int o = os_[s];
    const int r = (H0 * o) >> 8;
    const int sr = (r * 256) / o;
    r_[s]  = r;
    e_[s]  = ((r + 1) * 256 + o - 1) / o;
    s2_[s] = ((r + 1) * 256) / o;
    inv_[s] = 1.0f / (float)(e_[s] - sr);
    ax[s] = 0.f; ay[s] = 0.f; a2x[s] = 0.f; a2y[s] = 0.f;
  }
  #pragma unroll
  for (int g = 0; g < 4; ++g) {
    float2 vv[8];
    #pragma unroll
    for (int k = 0; k < 8; ++k) vv[k] = plane2[(H0 + g*8 + k) * 128 + w2];
    #pragma unroll
    for (int k = 0; k < 8; ++k) {
      const int h = H0 + g*8 + k;
      const float2 v = vv[k];
      #pragma unroll
      for (int s = 0; s < 7; ++s) {
        const int o = os_[s];
        ax[s] += v.x; ay[s] += v.y;
        if (h >= s2_[s]) { a2x[s] += v.x; a2y[s] += v.y; }
        if (h + 1 == e_[s]) {
          atomicAdd(&yh[ro_[s] + r_[s]][2*w2],     ax[s] * inv_[s]);
          atomicAdd(&yh[ro_[s] + r_[s]][2*w2 + 1], ay[s] * inv_[s]);
          r_[s]++;
          const int sr = s2_[s];
          e_[s]  = ((r_[s] + 1) * 256 + o - 1) / o;
          s2_[s] = ((r_[s] + 1) * 256) / o;
          inv_[s] = 1.0f / (float)(e_[s] - sr);
          ax[s] = a2x[s]; ay[s] = a2y[s];
          a2x[s] = 0.f; a2y[s] = 0.f;
        }
      }
    }
  }
  // flush in-progress segments (partials for segments crossing chunk end)
  #pragma unroll
  for (int s = 0; s < 7; ++s) {
    const int o = os_[s];
    if (r_[s] < o) {
      atomicAdd(&yh[ro_[s] + r_[s]][2*w2],     ax[s] * inv_[s]);
      atomicAdd(&yh[ro_[s] + r_[s]][2*w2 + 1], ay[s] * inv_[s]);
      if (r_[s] + 1 < o && s2_[s] < H0 + 32) {
        const int sr2 = s2_[s];
        const int e2  = ((r_[s] + 2) * 256 + o - 1) / o;
        const float inv2 = 1.0f / (float)(e2 - sr2);
        atomicAdd(&yh[ro_[s] + r_[s] + 1][2*w2],     a2x[s] * inv2);
        atomicAdd(&yh[ro_[s] + r_[s] + 1][2*w2 + 1], a2y[s] * inv2);
      }
    }
  }
}

// ---------------- kernel 1: multi-scale adaptive avg pools ----------------
__global__ __launch_bounds__(1024) void pool_kernel(
    const float* __restrict__ x5, const float* __restrict__ W_out,
    u16* __restrict__ wsK, u16* __restrict__ wsKT, u16* __restrict__ wsW,
    float* __restrict__ out)
{
  __shared__ float yh[54][257];
  const int tid = threadIdx.x;
  const int bc = blockIdx.x;          // b*128+c
  const int b  = bc >> 7;
  const int c  = bc & 127;
  const float2* plane2 = (const float2*)(x5 + (size_t)bc * NPIX);
  const int w2 = tid & 127;           // columns 2*w2, 2*w2+1
  const int q  = tid >> 7;            // row chunk 0..7 (wave-uniform)

  if (bc < 16) {                      // W f32 -> bf16, conv-fragment column perm
    const int idx = bc * 1024 + tid;
    const int o = idx >> 7, pp = idx & 127;
    const int q32 = pp >> 5, pos = pp & 31, g = pos >> 3, jj = pos & 7;
    const int csrc = q32 * 32 + ((jj < 4) ? (g * 4 + jj) : (16 + g * 4 + (jj - 4)));
    wsW[idx] = f2bf(W_out[o * 128 + csrc]);
  }

  // zero the accumulator tile
  for (int i = tid; i < 54 * 257; i += 1024) ((float*)yh)[i] = 0.f;
  __syncthreads();

  switch (q) {
    case 0: pool_phaseA<0>  (plane2, yh, w2); break;
    case 1: pool_phaseA<32> (plane2, yh, w2); break;
    case 2: pool_phaseA<64> (plane2, yh, w2); break;
    case 3: pool_phaseA<96> (plane2, yh, w2); break;
    case 4: pool_phaseA<128>(plane2, yh, w2); break;
    case 5: pool_phaseA<160>(plane2, yh, w2); break;
    case 6: pool_phaseA<192>(plane2, yh, w2); break;
    default: pool_phaseA<224>(plane2, yh, w2); break;
  }
  __syncthreads();

  // zero key-padding 396..399
  if (tid < NKP - NK) {
    wsK [((size_t)b * NKP + NK + tid) * C_N + c] = 0;
    wsKT[(size_t)bc * NKP + NK + tid] = 0;
  }

  // Phase B: 64 groups of 16 lanes; each group reduces one output per iter
  const int grp = tid >> 4;
  const int gl  = tid & 15;
  #pragma unroll
  for (int it = 0; it < 9; ++it) {
    const int r = grp + it * 64;
    int rr = r;
    int o, ro, kbase, dst;   // dst: 0=Key, 1=p12, 2=p6
    if      (rr < 256) { o = 16; ro = 0;  kbase = 140; dst = 0; }
    else if (rr < 400) { o = 12; ro = 16; kbase = 0;   dst = 1; rr -= 256; }
    else if (rr < 481) { o = 9;  ro = 28; kbase = 10;  dst = 0; rr -= 400; }
    else if (rr < 530) { o = 7;  ro = 37; kbase = 91;  dst = 0; rr -= 481; }
    else if (rr < 566) { o = 6;  ro = 44; kbase = 0;   dst = 2; rr -= 530; }
    else if (rr < 575) { o = 3;  ro = 50; kbase = 0;   dst = 0; rr -= 566; }
    else               { o = 1;  ro = 53; kbase = 9;   dst = 0; rr = 0;   }
    const int i = rr / o;
    const int j = rr - i * o;
    const int s = (j * HW_) / o;
    const int e = ((j + 1) * HW_ + o - 1) / o;
    float partial = 0.f;
    const float* row = yh[ro + i];
    for (int wq = s + gl; wq < e; wq += 16) partial += row[wq];
    partial += __shfl_xor(partial, 1);
    partial += __shfl_xor(partial, 2);
    partial += __shfl_xor(partial, 4);
    partial += __shfl_xor(partial, 8);
    if (gl == 0) {
      const float v = partial * (1.0f / (float)(e - s));
      if (dst == 1) {
        out[P12_OFF + (size_t)bc * 144 + rr] = v;
      } else if (dst == 2) {
        out[P6_OFF + (size_t)bc * 36 + rr] = v;
      } else {
        const int key = kbase + rr;
        const u16 bv = f2bf(v);
        wsK [((size_t)b * NKP + key) * C_N + c] = bv;   // [b][key][c]
        wsKT[(size_t)bc * NKP + key]            = bv;   // [b][c][key]
      }
    }
  }
}

// ---------------- attn staging helpers (256 threads = 4 waves) ------------
// K rows staged PERMUTED: tile j, row rit=4*wv+lr holds global key
// CB + (j>>1)*32 + 8*wv + (j&1)*4 + lr, so each lane's 8 scores across a
// tile pair are keys 8*l4..8*l4+7 (natural order) -> P is lane-local.
template<int CB, int BUF>
static __device__ __forceinline__ void stage64(
    char* smem, const char* wsKb, const char* wsKTb, int wv, int lane)
{
  char* buf = smem + BUF * BUFSZ;
  const int lr = lane >> 4, lc = lane & 15;
  const int rit = wv * 4 + lr;                            // dest row in tile
  #pragma unroll
  for (int j = 0; j < 4; ++j) {
    const int gk = CB + (j >> 1) * 32 + wv * 8 + ((j & 1) << 2) + lr;
    gl_lds16(wsKb + (size_t)gk * 256 + ((lc ^ rit) << 4),
             buf + j*4096 + wv*1024);
    const int vrow = j*32 + wv*8 + (lane >> 3);           // 128 c rows x 128B
    gl_lds16(wsKTb + (size_t)vrow * (NKP*2) + CB*2 + (((lane & 7) ^ (vrow & 7)) << 4),
             buf + VT_OFF + j*4096 + wv*1024);
  }
}

static __device__ __forceinline__ void stage_tail(
    char* buf, const char* wsKb, const char* wsKTb, int wv, int lane)
{
  const int lr = lane >> 4;
  const int rit = wv * 4 + lr;
  #pragma unroll
  for (int j = 0; j < 2; ++j) {  // K: 2 permuted tiles; keys >=396 zeroed/masked
    const int gk = 384 + wv * 8 + (j << 2) + lr;          // up to 415: in-ws garbage, masked
    gl_lds16(wsKb + (size_t)gk * 256 + (((lane & 15) ^ rit) << 4),
             buf + j*4096 + wv*1024);
  }
  #pragma unroll
  for (int j = 0; j < 2; ++j) {  // VT: 128 rows x 64B (32B real + 32B overread)
    const int row = j*64 + wv*16 + (lane >> 2);
    gl_lds16(wsKTb + (size_t)row * (NKP*2) + 768 + ((lane & 3) << 4),
             buf + VT_OFF + j*4096 + wv*1024);
  }
}

static __device__ __forceinline__ void stage_W(
    char* smem, const u16* wsW, int wv, int lane)
{
  #pragma unroll
  for (int j = 0; j < 8; ++j) {   // 128 rows x 256B bf16 -> buf1
    const int row = j*16 + wv*4 + (lane >> 4);
    gl_lds16((const char*)wsW + (size_t)row * 256 + (((lane & 15) ^ (row & 15)) << 4),
             smem + BUFSZ + j*4096 + wv*1024);
  }
}

// ------ per-64-key chunk: QK^T -> exp -> PV; P stays in registers --------
template<int BUF, int TAIL>
static __device__ __forceinline__ void compute64(
    char* smem, const bf16x8 (&qf)[2][4],
    f32x4 (&agg)[8][2], float (&d)[2], int l15, int l4)
{
  const char* buf = smem + BUF * BUFSZ;
  constexpr int NT   = TAIL ? 2 : 4;
  constexpr int SUBS = TAIL ? 1 : 2;

  f32x4 sA[NT][2];
  #pragma unroll
  for (int nt = 0; nt < NT; ++nt) {
    sA[nt][0] = (f32x4){0.f,0.f,0.f,0.f};
    sA[nt][1] = (f32x4){0.f,0.f,0.f,0.f};
  }
  #pragma unroll
  for (int nt = 0; nt < NT; ++nt) {
    bf16x8 kf[4];
    #pragma unroll
    for (int kc = 0; kc < 4; ++kc)
      kf[kc] = *(const bf16x8*)(buf + (nt*16 + l15) * 256 +
                                ((kc*64 + l4*16) ^ (l15 << 4)));
    #pragma unroll
    for (int kc = 0; kc < 4; ++kc) {
      sA[nt][0] = MFMA32(kf[kc], qf[0][kc], sA[nt][0], 0, 0, 0);
      sA[nt][1] = MFMA32(kf[kc], qf[1][kc], sA[nt][1], 0, 0, 0);
    }
  }

  #pragma unroll
  for (int sub = 0; sub < SUBS; ++sub) {
    bf16x8 pf[2];
    #pragma unroll
    for (int pt = 0; pt < 2; ++pt) {
      float e[8];
      #pragma unroll
      for (int qi = 0; qi < 4; ++qi) e[qi]     = exp2f(sA[2*sub][pt][qi]);
      #pragma unroll
      for (int qi = 0; qi < 4; ++qi) e[4 + qi] = exp2f(sA[2*sub + 1][pt][qi]);
      if (TAIL) {
        #pragma unroll
        for (int j = 0; j < 8; ++j) if (l4*8 + j >= 12) e[j] = 0.f;
      }
      d[pt] += ((e[0]+e[1]) + (e[2]+e[3])) + ((e[4]+e[5]) + (e[6]+e[7]));
      bf16x8 t;
      #pragma unroll
      for (int j = 0; j < 8; ++j) t[j] = (short)f2bf(e[j]);
      pf[pt] = t;
    }
    #pragma unroll
    for (int ct = 0; ct < 8; ++ct) {
      const int vrow = ct*16 + l15;
      bf16x8 vf;
      if (TAIL)
        vf = *(const bf16x8*)(buf + VT_OFF + vrow*64 + l4*16);
      else
        vf = *(const bf16x8*)(buf + VT_OFF + vrow*128 +
                              ((sub*64 + l4*16) ^ ((vrow & 7) << 4)));
      agg[ct][0] = MFMA32(vf, pf[0], agg[ct][0], 0, 0, 0);
      agg[ct][1] = MFMA32(vf, pf[1], agg[ct][1], 0, 0, 0);
    }
  }
}

// -------- kernel 2: MFMA attention + 1x1 conv + bias + residual --------
__global__ __launch_bounds__(256, 2) void attn_kernel(
    const float* __restrict__ x5, const u16* __restrict__ wsK,
    const u16* __restrict__ wsKT, const u16* __restrict__ wsW,
    const float* __restrict__ b_out, float* __restrict__ out)
{
  extern __shared__ char smem[];
  const int tid  = threadIdx.x;
  // bijective XCD swizzle: 2048 blocks, 8 XCDs, 256 contiguous per XCD
  const int wgid = (blockIdx.x & 7) * 256 + (blockIdx.x >> 3);
  const int b    = wgid >> 9;
  const int pix0 = (wgid & 511) << 7;
  const int lane = tid & 63, wv = tid >> 6;
  const int l15  = lane & 15, l4 = lane >> 4;
  const float SCL2 = 0.044194173824159216f * 1.4426950408889634f;

  const char* wsKb  = (const char*)wsK  + (size_t)b * NKP * C_N * 2;
  const char* wsKTb = (const char*)wsKT + (size_t)b * C_N * NKP * 2;

  // ---- stage Q [128 pix][128 c] bf16 into buf0 (scale folded in) ----
  {
    const float* r0p = x5 + (((size_t)(b * C_N + 2*lane)) << 16) + pix0 + wv * 32;
    const float* r1p = r0p + NPIX;
    float4 v0[8], v1[8];
    #pragma unroll
    for (int j = 0; j < 8; ++j) {
      v0[j] = *(const float4*)(r0p + j*4);
      v1[j] = *(const float4*)(r1p + j*4);
    }
    #pragma unroll
    for (int i = 0; i < 32; ++i) {
      const int pix = wv * 32 + i;
      const unsigned pk = pack2(((const float*)&v0[i>>2])[i&3] * SCL2,
                                ((const float*)&v1[i>>2])[i&3] * SCL2);
      *(unsigned*)(smem + pix * 256 + ((lane*4) ^ ((pix & 15) << 4))) = pk;
    }
  }
  __syncthreads();

  bf16x8 qf[2][4];
  #pragma unroll
  for (int pt = 0; pt < 2; ++pt)
    #pragma unroll
    for (int kc = 0; kc < 4; ++kc)
      qf[pt][kc] = *(const bf16x8*)(smem + (wv*32 + pt*16 + l15) * 256 +
                                    ((kc*64 + l4*16) ^ (l15 << 4)));
  __syncthreads();

  f32x4 agg[8][2];
  #pragma unroll
  for (int ct = 0; ct < 8; ++ct) {
    agg[ct][0] = (f32x4){0.f,0.f,0.f,0.f};
    agg[ct][1] = (f32x4){0.f,0.f,0.f,0.f};
  }
  float d[2] = {0.f, 0.f};

  // ---- chunk pipeline: counted vmcnt keeps next-chunk loads in flight ----
  stage64<0, 0>(smem, wsKb, wsKTb, wv, lane);
  stage64<64, 1>(smem, wsKb, wsKTb, wv, lane);
  VM8(); BAR();                                  // chunk0 landed; chunk1 flying
  compute64<0, 0>(smem, qf, agg, d, l15, l4);
  BAR();                                         // all waves done reading buf0

  stage64<128, 0>(smem, wsKb, wsKTb, wv, lane);
  VM8(); BAR();
  compute64<1, 0>(smem, qf, agg, d, l15, l4);
  BAR();

  stage64<192, 1>(smem, wsKb, wsKTb, wv, lane);
  VM8(); BAR();
  compute64<0, 0>(smem, qf, agg, d, l15, l4);
  BAR();

  stage64<256, 0>(smem, wsKb, wsKTb, wv, lane);
  VM8(); BAR();
  compute64<1, 0>(smem, qf, agg, d, l15, l4);
  BAR();

  stage64<320, 1>(smem, wsKb, wsKTb, wv, lane);
  VM8(); BAR();
  compute64<0, 0>(smem, qf, agg, d, l15, l4);
  BAR();

  stage_tail(smem, wsKb, wsKTb, wv, lane);       // tail -> buf0 (4 loads/wave)
  VM4(); BAR();                                  // chunk5 landed; tail flying
  compute64<1, 0>(smem, qf, agg, d, l15, l4);
  BAR();

  stage_W(smem, wsW, wv, lane);                  // W bf16 (permuted) -> buf1
  asm volatile("s_waitcnt vmcnt(0)" ::: "memory");
  __syncthreads();   // full drain (tail + W)

  compute64<0, 1>(smem, qf, agg, d, l15, l4);    // tail (buf0)
  // everything below is per-wave; no more block barriers needed

  // denominator over the 4 l4-groups sharing pixel l15
  float inv[2];
  #pragma unroll
  for (int pt = 0; pt < 2; ++pt) {
    float s = d[pt];
    s += __shfl_xor(s, 16);
    s += __shfl_xor(s, 32);
    inv[pt] = 1.0f / s;
  }

  // conv: lane-local AGG B-fragments (wsW column-permuted to match)
  f32x4 cacc[8][2];
  #pragma unroll
  for (int ot = 0; ot < 8; ++ot) {
    cacc[ot][0] = (f32x4){0.f,0.f,0.f,0.f};
    cacc[ot][1] = (f32x4){0.f,0.f,0.f,0.f};
  }
  #pragma unroll
  for (int qh = 0; qh < 4; ++qh) {
    bf16x8 agf[2];
    #pragma unroll
    for (int pt = 0; pt < 2; ++pt) {
      bf16x8 t;
      #pragma unroll
      for (int j = 0; j < 8; ++j)
        t[j] = (short)f2bf(agg[2*qh + (j >> 2)][pt][j & 3] * inv[pt]);
      agf[pt] = t;
    }
    #pragma unroll
    for (int ot = 0; ot < 8; ++ot) {
      const bf16x8 wa = *(const bf16x8*)(smem + BUFSZ + (ot*16 + l15) * 256 +
                                         ((qh*64 + l4*16) ^ (l15 << 4)));
      cacc[ot][0] = MFMA32(wa, agf[0], cacc[ot][0], 0, 0, 0);
      cacc[ot][1] = MFMA32(wa, agf[1], cacc[ot][1], 0, 0, 0);
    }
  }

  // store: + bias + residual
  #pragma unroll
  for (int ot = 0; ot < 8; ++ot) {
    const float4 bq = *(const float4*)(b_out + ot*16 + l4*4);
    #pragma unroll
    for (int pt = 0; pt < 2; ++pt) {
      #pragma unroll
      for (int qi = 0; qi < 4; ++qi) {
        const int o = ot*16 + l4*4 + qi;
        const size_t idx = (((size_t)(b * C_N + o)) << 16) + pix0 + wv*32 + pt*16 + l15;
        out[idx] = cacc[ot][pt][qi] + ((const float*)&bq)[qi] + x5[idx];
      }
    }
  }
}

extern "C" void kernel_launch(void* const* d_in, const int* in_sizes, int n_in,
                              void* d_out, int out_size, void* d_ws, size_t ws_size,
                              hipStream_t stream) {
  const float* x5    = (const float*)d_in[0];
  const float* W_out = (const float*)d_in[1];
  const float* b_out = (const float*)d_in[2];
  float* out = (float*)d_out;
  // ws layout: wsKT first (tail staging overreads past rows; lands in wsK/wsW)
  u16* wsKT = (u16*)d_ws;                                        // [4][128][400] bf16
  u16* wsK  = (u16*)((char*)d_ws + (size_t)B_N * C_N * NKP * 2); // [4][400][128] bf16
  u16* wsW  = (u16*)((char*)d_ws + (size_t)2 * B_N * C_N * NKP * 2); // [128][128] bf16

  pool_kernel<<<512, 1024, 0, stream>>>(x5, W_out, wsK, wsKT, wsW, out);

  hipFuncSetAttribute((const void*)attn_kernel,
                      hipFuncAttributeMaxDynamicSharedMemorySize, LDS_BYTES);
  attn_kernel<<<B_N * 512, 256, LDS_BYTES, stream>>>(x5, wsK, wsKT, wsW, b_out, out);
}

// Round 22
// 174.483 us; speedup vs baseline: 3.3541x; 1.0421x over previous
//
#include <hip/hip_runtime.h>
#include <hip/hip_bf16.h>

typedef short bf16x8 __attribute__((ext_vector_type(8)));
typedef float f32x4  __attribute__((ext_vector_type(4)));
typedef unsigned short u16;

#define B_N 4
#define C_N 128
#define HW_ 256
#define NPIX 65536
#define NK 396
#define NKP 400
#define OUT_MAIN ((size_t)B_N * C_N * NPIX)
#define P12_OFF OUT_MAIN
#define P6_OFF  (P12_OFF + (size_t)B_N * C_N * 144)

// attn LDS arena: two 32KB buffers (K 16KB + VT 16KB each); no P region
#define BUFSZ  32768
#define VT_OFF 16384
#define LDS_BYTES 65536

static __device__ __forceinline__ u16 f2bf(float x) {
  __hip_bfloat16 h = __float2bfloat16(x);
  return *(u16*)&h;
}
static __device__ __forceinline__ unsigned pack2(float lo, float hi) {
  return ((unsigned)f2bf(hi) << 16) | f2bf(lo);
}
static __device__ __forceinline__ void gl_lds16(const void* g, void* l) {
  __builtin_amdgcn_global_load_lds(
      (const __attribute__((address_space(1))) unsigned*)g,
      (__attribute__((address_space(3))) unsigned*)l, 16, 0, 0);
}
#define MFMA32 __builtin_amdgcn_mfma_f32_16x16x32_bf16
#define BAR() do { __builtin_amdgcn_s_barrier(); \
                   __builtin_amdgcn_sched_barrier(0); } while (0)
#define VM8() do { asm volatile("s_waitcnt vmcnt(8)" ::: "memory"); \
                   __builtin_amdgcn_sched_barrier(0); } while (0)
#define VM4() do { asm volatile("s_waitcnt vmcnt(4)" ::: "memory"); \
                   __builtin_amdgcn_sched_barrier(0); } while (0)

// ---- pool Phase A, prefix-sum form. H0 compile-time: all segment bounds
// fold; per element just 2 adds; contributions are prefix differences
// emitted at compile-time-known rows via LDS atomics (same partial set and
// inv scaling as the state-machine version; only intra-chunk rounding
// differs, ~1e-6).
template<int H0>
static __device__ __forceinline__ void pool_phaseA(
    const float2* __restrict__ plane2, float (*yh)[257], int w2)
{
  const int os_[7] = {16,12,9,7,6,3,1};
  const int ro_[7] = {0,16,28,37,44,50,53};
  float rx = 0.f, ry = 0.f;
  float snx[7][2], sny[7][2];
  #pragma unroll
  for (int g = 0; g < 4; ++g) {
    float2 vv[8];
    #pragma unroll
    for (int k = 0; k < 8; ++k) vv[k] = plane2[(H0 + g*8 + k) * 128 + w2];
    #pragma unroll
    for (int k = 0; k < 8; ++k) {
      const int h = H0 + g*8 + k;
      // segment-start snapshots (P[h], before adding row h)
      #pragma unroll
      for (int s = 0; s < 7; ++s) {
        #pragma unroll
        for (int r = 0; r < 16; ++r) {
          const int o = os_[s];
          if (r < o) {
            const int sr = (r * 256) / o;
            const int er = ((r + 1) * 256 + o - 1) / o;
            const int cs = (sr < H0) ? H0 : sr;
            if (er > H0 && sr < H0 + 32 && cs == h) {
              snx[s][r & 1] = rx; sny[s][r & 1] = ry;
            }
          }
        }
      }
      rx += vv[k].x; ry += vv[k].y;
      // segment-end emissions (P[h+1], after adding row h)
      #pragma unroll
      for (int s = 0; s < 7; ++s) {
        #pragma unroll
        for (int r = 0; r < 16; ++r) {
          const int o = os_[s];
          if (r < o) {
            const int sr = (r * 256) / o;
            const int er = ((r + 1) * 256 + o - 1) / o;
            const int ce = (er > H0 + 32) ? (H0 + 32) : er;
            if (er > H0 && sr < H0 + 32 && ce == h + 1) {
              const float inv = 1.0f / (float)(er - sr);
              atomicAdd(&yh[ro_[s] + r][2*w2],     (rx - snx[s][r & 1]) * inv);
              atomicAdd(&yh[ro_[s] + r][2*w2 + 1], (ry - sny[s][r & 1]) * inv);
            }
          }
        }
      }
    }
  }
}

// ---------------- kernel 1: multi-scale adaptive avg pools ----------------
__global__ __launch_bounds__(1024) void pool_kernel(
    const float* __restrict__ x5, const float* __restrict__ W_out,
    u16* __restrict__ wsK, u16* __restrict__ wsKT, u16* __restrict__ wsW,
    float* __restrict__ out)
{
  __shared__ float yh[54][257];
  const int tid = threadIdx.x;
  const int bc = blockIdx.x;          // b*128+c
  const int b  = bc >> 7;
  const int c  = bc & 127;
  const float2* plane2 = (const float2*)(x5 + (size_t)bc * NPIX);
  const int w2 = tid & 127;           // columns 2*w2, 2*w2+1
  const int q  = tid >> 7;            // row chunk 0..7 (wave-uniform)

  if (bc < 16) {                      // W f32 -> bf16, conv-fragment column perm
    const int idx = bc * 1024 + tid;
    const int o = idx >> 7, pp = idx & 127;
    const int q32 = pp >> 5, pos = pp & 31, g = pos >> 3, jj = pos & 7;
    const int csrc = q32 * 32 + ((jj < 4) ? (g * 4 + jj) : (16 + g * 4 + (jj - 4)));
    wsW[idx] = f2bf(W_out[o * 128 + csrc]);
  }

  // zero the accumulator tile
  for (int i = tid; i < 54 * 257; i += 1024) ((float*)yh)[i] = 0.f;
  __syncthreads();

  switch (q) {
    case 0: pool_phaseA<0>  (plane2, yh, w2); break;
    case 1: pool_phaseA<32> (plane2, yh, w2); break;
    case 2: pool_phaseA<64> (plane2, yh, w2); break;
    case 3: pool_phaseA<96> (plane2, yh, w2); break;
    case 4: pool_phaseA<128>(plane2, yh, w2); break;
    case 5: pool_phaseA<160>(plane2, yh, w2); break;
    case 6: pool_phaseA<192>(plane2, yh, w2); break;
    default: pool_phaseA<224>(plane2, yh, w2); break;
  }
  __syncthreads();

  // zero key-padding 396..399
  if (tid < NKP - NK) {
    wsK [((size_t)b * NKP + NK + tid) * C_N + c] = 0;
    wsKT[(size_t)bc * NKP + NK + tid] = 0;
  }

  // Phase B: 64 groups of 16 lanes; each group reduces one output per iter
  const int grp = tid >> 4;
  const int gl  = tid & 15;
  #pragma unroll
  for (int it = 0; it < 9; ++it) {
    const int r = grp + it * 64;
    int rr = r;
    int o, ro, kbase, dst;   // dst: 0=Key, 1=p12, 2=p6
    if      (rr < 256) { o = 16; ro = 0;  kbase = 140; dst = 0; }
    else if (rr < 400) { o = 12; ro = 16; kbase = 0;   dst = 1; rr -= 256; }
    else if (rr < 481) { o = 9;  ro = 28; kbase = 10;  dst = 0; rr -= 400; }
    else if (rr < 530) { o = 7;  ro = 37; kbase = 91;  dst = 0; rr -= 481; }
    else if (rr < 566) { o = 6;  ro = 44; kbase = 0;   dst = 2; rr -= 530; }
    else if (rr < 575) { o = 3;  ro = 50; kbase = 0;   dst = 0; rr -= 566; }
    else               { o = 1;  ro = 53; kbase = 9;   dst = 0; rr = 0;   }
    const int i = rr / o;
    const int j = rr - i * o;
    const int s = (j * HW_) / o;
    const int e = ((j + 1) * HW_ + o - 1) / o;
    float partial = 0.f;
    const float* row = yh[ro + i];
    for (int wq = s + gl; wq < e; wq += 16) partial += row[wq];
    partial += __shfl_xor(partial, 1);
    partial += __shfl_xor(partial, 2);
    partial += __shfl_xor(partial, 4);
    partial += __shfl_xor(partial, 8);
    if (gl == 0) {
      const float v = partial * (1.0f / (float)(e - s));
      if (dst == 1) {
        out[P12_OFF + (size_t)bc * 144 + rr] = v;
      } else if (dst == 2) {
        out[P6_OFF + (size_t)bc * 36 + rr] = v;
      } else {
        const int key = kbase + rr;
        const u16 bv = f2bf(v);
        wsK [((size_t)b * NKP + key) * C_N + c] = bv;   // [b][key][c]
        wsKT[(size_t)bc * NKP + key]            = bv;   // [b][c][key]
      }
    }
  }
}

// ---------------- attn staging helpers (256 threads = 4 waves) ------------
// K rows staged PERMUTED: tile j, row rit=4*wv+lr holds global key
// CB + (j>>1)*32 + 8*wv + (j&1)*4 + lr, so each lane's 8 scores across a
// tile pair are keys 8*l4..8*l4+7 (natural order) -> P is lane-local.
template<int CB, int BUF>
static __device__ __forceinline__ void stage64(
    char* smem, const char* wsKb, const char* wsKTb, int wv, int lane)
{
  char* buf = smem + BUF * BUFSZ;
  const int lr = lane >> 4, lc = lane & 15;
  const int rit = wv * 4 + lr;                            // dest row in tile
  #pragma unroll
  for (int j = 0; j < 4; ++j) {
    const int gk = CB + (j >> 1) * 32 + wv * 8 + ((j & 1) << 2) + lr;
    gl_lds16(wsKb + (size_t)gk * 256 + ((lc ^ rit) << 4),
             buf + j*4096 + wv*1024);
    const int vrow = j*32 + wv*8 + (lane >> 3);           // 128 c rows x 128B
    gl_lds16(wsKTb + (size_t)vrow * (NKP*2) + CB*2 + (((lane & 7) ^ (vrow & 7)) << 4),
             buf + VT_OFF + j*4096 + wv*1024);
  }
}

static __device__ __forceinline__ void stage_tail(
    char* buf, const char* wsKb, const char* wsKTb, int wv, int lane)
{
  const int lr = lane >> 4;
  const int rit = wv * 4 + lr;
  #pragma unroll
  for (int j = 0; j < 2; ++j) {  // K: 2 permuted tiles; keys >=396 zeroed/masked
    const int gk = 384 + wv * 8 + (j << 2) + lr;          // up to 415: in-ws garbage, masked
    gl_lds16(wsKb + (size_t)gk * 256 + (((lane & 15) ^ rit) << 4),
             buf + j*4096 + wv*1024);
  }
  #pragma unroll
  for (int j = 0; j < 2; ++j) {  // VT: 128 rows x 64B (32B real + 32B overread)
    const int row = j*64 + wv*16 + (lane >> 2);
    gl_lds16(wsKTb + (size_t)row * (NKP*2) + 768 + ((lane & 3) << 4),
             buf + VT_OFF + j*4096 + wv*1024);
  }
}

static __device__ __forceinline__ void stage_W(
    char* smem, const u16* wsW, int wv, int lane)
{
  #pragma unroll
  for (int j = 0; j < 8; ++j) {   // 128 rows x 256B bf16 -> buf1
    const int row = j*16 + wv*4 + (lane >> 4);
    gl_lds16((const char*)wsW + (size_t)row * 256 + (((lane & 15) ^ (row & 15)) << 4),
             smem + BUFSZ + j*4096 + wv*1024);
  }
}

// ------ per-64-key chunk: QK^T -> exp -> PV; P stays in registers --------
template<int BUF, int TAIL>
static __device__ __forceinline__ void compute64(
    char* smem, const bf16x8 (&qf)[2][4],
    f32x4 (&agg)[8][2], float (&d)[2], int l15, int l4)
{
  const char* buf = smem + BUF * BUFSZ;
  constexpr int NT   = TAIL ? 2 : 4;
  constexpr int SUBS = TAIL ? 1 : 2;

  f32x4 sA[NT][2];
  #pragma unroll
  for (int nt = 0; nt < NT; ++nt) {
    sA[nt][0] = (f32x4){0.f,0.f,0.f,0.f};
    sA[nt][1] = (f32x4){0.f,0.f,0.f,0.f};
  }
  #pragma unroll
  for (int nt = 0; nt < NT; ++nt) {
    bf16x8 kf[4];
    #pragma unroll
    for (int kc = 0; kc < 4; ++kc)
      kf[kc] = *(const bf16x8*)(buf + (nt*16 + l15) * 256 +
                                ((kc*64 + l4*16) ^ (l15 << 4)));
    #pragma unroll
    for (int kc = 0; kc < 4; ++kc) {
      sA[nt][0] = MFMA32(kf[kc], qf[0][kc], sA[nt][0], 0, 0, 0);
      sA[nt][1] = MFMA32(kf[kc], qf[1][kc], sA[nt][1], 0, 0, 0);
    }
  }

  #pragma unroll
  for (int sub = 0; sub < SUBS; ++sub) {
    bf16x8 pf[2];
    #pragma unroll
    for (int pt = 0; pt < 2; ++pt) {
      float e[8];
      #pragma unroll
      for (int qi = 0; qi < 4; ++qi) e[qi]     = exp2f(sA[2*sub][pt][qi]);
      #pragma unroll
      for (int qi = 0; qi < 4; ++qi) e[4 + qi] = exp2f(sA[2*sub + 1][pt][qi]);
      if (TAIL) {
        #pragma unroll
        for (int j = 0; j < 8; ++j) if (l4*8 + j >= 12) e[j] = 0.f;
      }
      d[pt] += ((e[0]+e[1]) + (e[2]+e[3])) + ((e[4]+e[5]) + (e[6]+e[7]));
      bf16x8 t;
      #pragma unroll
      for (int j = 0; j < 8; ++j) t[j] = (short)f2bf(e[j]);
      pf[pt] = t;
    }
    #pragma unroll
    for (int ct = 0; ct < 8; ++ct) {
      const int vrow = ct*16 + l15;
      bf16x8 vf;
      if (TAIL)
        vf = *(const bf16x8*)(buf + VT_OFF + vrow*64 + l4*16);
      else
        vf = *(const bf16x8*)(buf + VT_OFF + vrow*128 +
                              ((sub*64 + l4*16) ^ ((vrow & 7) << 4)));
      agg[ct][0] = MFMA32(vf, pf[0], agg[ct][0], 0, 0, 0);
      agg[ct][1] = MFMA32(vf, pf[1], agg[ct][1], 0, 0, 0);
    }
  }
}

// -------- kernel 2: MFMA attention + 1x1 conv + bias + residual --------
__global__ __launch_bounds__(256, 2) void attn_kernel(
    const float* __restrict__ x5, const u16* __restrict__ wsK,
    const u16* __restrict__ wsKT, const u16* __restrict__ wsW,
    const float* __restrict__ b_out, float* __restrict__ out)
{
  extern __shared__ char smem[];
  const int tid  = threadIdx.x;
  // bijective XCD swizzle: 2048 blocks, 8 XCDs, 256 contiguous per XCD
  const int wgid = (blockIdx.x & 7) * 256 + (blockIdx.x >> 3);
  const int b    = wgid >> 9;
  const int pix0 = (wgid & 511) << 7;
  const int lane = tid & 63, wv = tid >> 6;
  const int l15  = lane & 15, l4 = lane >> 4;
  const float SCL2 = 0.044194173824159216f * 1.4426950408889634f;

  const char* wsKb  = (const char*)wsK  + (size_t)b * NKP * C_N * 2;
  const char* wsKTb = (const char*)wsKT + (size_t)b * C_N * NKP * 2;

  // ---- stage Q [128 pix][128 c] bf16 into buf0 (scale folded in) ----
  {
    const float* r0p = x5 + (((size_t)(b * C_N + 2*lane)) << 16) + pix0 + wv * 32;
    const float* r1p = r0p + NPIX;
    float4 v0[8], v1[8];
    #pragma unroll
    for (int j = 0; j < 8; ++j) {
      v0[j] = *(const float4*)(r0p + j*4);
      v1[j] = *(const float4*)(r1p + j*4);
    }
    #pragma unroll
    for (int i = 0; i < 32; ++i) {
      const int pix = wv * 32 + i;
      const unsigned pk = pack2(((const float*)&v0[i>>2])[i&3] * SCL2,
                                ((const float*)&v1[i>>2])[i&3] * SCL2);
      *(unsigned*)(smem + pix * 256 + ((lane*4) ^ ((pix & 15) << 4))) = pk;
    }
  }
  __syncthreads();

  bf16x8 qf[2][4];
  #pragma unroll
  for (int pt = 0; pt < 2; ++pt)
    #pragma unroll
    for (int kc = 0; kc < 4; ++kc)
      qf[pt][kc] = *(const bf16x8*)(smem + (wv*32 + pt*16 + l15) * 256 +
                                    ((kc*64 + l4*16) ^ (l15 << 4)));
  __syncthreads();

  f32x4 agg[8][2];
  #pragma unroll
  for (int ct = 0; ct < 8; ++ct) {
    agg[ct][0] = (f32x4){0.f,0.f,0.f,0.f};
    agg[ct][1] = (f32x4){0.f,0.f,0.f,0.f};
  }
  float d[2] = {0.f, 0.f};

  // ---- chunk pipeline: counted vmcnt keeps next-chunk loads in flight ----
  stage64<0, 0>(smem, wsKb, wsKTb, wv, lane);
  stage64<64, 1>(smem, wsKb, wsKTb, wv, lane);
  VM8(); BAR();                                  // chunk0 landed; chunk1 flying
  compute64<0, 0>(smem, qf, agg, d, l15, l4);
  BAR();                                         // all waves done reading buf0

  stage64<128, 0>(smem, wsKb, wsKTb, wv, lane);
  VM8(); BAR();
  compute64<1, 0>(smem, qf, agg, d, l15, l4);
  BAR();

  stage64<192, 1>(smem, wsKb, wsKTb, wv, lane);
  VM8(); BAR();
  compute64<0, 0>(smem, qf, agg, d, l15, l4);
  BAR();

  stage64<256, 0>(smem, wsKb, wsKTb, wv, lane);
  VM8(); BAR();
  compute64<1, 0>(smem, qf, agg, d, l15, l4);
  BAR();

  stage64<320, 1>(smem, wsKb, wsKTb, wv, lane);
  VM8(); BAR();
  compute64<0, 0>(smem, qf, agg, d, l15, l4);
  BAR();

  stage_tail(smem, wsKb, wsKTb, wv, lane);       // tail -> buf0 (4 loads/wave)
  VM4(); BAR();                                  // chunk5 landed; tail flying
  compute64<1, 0>(smem, qf, agg, d, l15, l4);
  BAR();

  stage_W(smem, wsW, wv, lane);                  // W bf16 (permuted) -> buf1
  asm volatile("s_waitcnt vmcnt(0)" ::: "memory");
  __syncthreads();   // full drain (tail + W)

  compute64<0, 1>(smem, qf, agg, d, l15, l4);    // tail (buf0)
  // everything below is per-wave; no more block barriers needed

  // denominator over the 4 l4-groups sharing pixel l15
  float inv[2];
  #pragma unroll
  for (int pt = 0; pt < 2; ++pt) {
    float s = d[pt];
    s += __shfl_xor(s, 16);
    s += __shfl_xor(s, 32);
    inv[pt] = 1.0f / s;
  }

  // conv: lane-local AGG B-fragments (wsW column-permuted to match)
  f32x4 cacc[8][2];
  #pragma unroll
  for (int ot = 0; ot < 8; ++ot) {
    cacc[ot][0] = (f32x4){0.f,0.f,0.f,0.f};
    cacc[ot][1] = (f32x4){0.f,0.f,0.f,0.f};
  }
  #pragma unroll
  for (int qh = 0; qh < 4; ++qh) {
    bf16x8 agf[2];
    #pragma unroll
    for (int pt = 0; pt < 2; ++pt) {
      bf16x8 t;
      #pragma unroll
      for (int j = 0; j < 8; ++j)
        t[j] = (short)f2bf(agg[2*qh + (j >> 2)][pt][j & 3] * inv[pt]);
      agf[pt] = t;
    }
    #pragma unroll
    for (int ot = 0; ot < 8; ++ot) {
      const bf16x8 wa = *(const bf16x8*)(smem + BUFSZ + (ot*16 + l15) * 256 +
                                         ((qh*64 + l4*16) ^ (l15 << 4)));
      cacc[ot][0] = MFMA32(wa, agf[0], cacc[ot][0], 0, 0, 0);
      cacc[ot][1] = MFMA32(wa, agf[1], cacc[ot][1], 0, 0, 0);
    }
  }

  // store: + bias + residual
  #pragma unroll
  for (int ot = 0; ot < 8; ++ot) {
    const float4 bq = *(const float4*)(b_out + ot*16 + l4*4);
    #pragma unroll
    for (int pt = 0; pt < 2; ++pt) {
      #pragma unroll
      for (int qi = 0; qi < 4; ++qi) {
        const int o = ot*16 + l4*4 + qi;
        const size_t idx = (((size_t)(b * C_N + o)) << 16) + pix0 + wv*32 + pt*16 + l15;
        out[idx] = cacc[ot][pt][qi] + ((const float*)&bq)[qi] + x5[idx];
      }
    }
  }
}

extern "C" void kernel_launch(void* const* d_in, const int* in_sizes, int n_in,
                              void* d_out, int out_size, void* d_ws, size_t ws_size,
                              hipStream_t stream) {
  const float* x5    = (const float*)d_in[0];
  const float* W_out = (const float*)d_in[1];
  const float* b_out = (const float*)d_in[2];
  float* out = (float*)d_out;
  // ws layout: wsKT first (tail staging overreads past rows; lands in wsK/wsW)
  u16* wsKT = (u16*)d_ws;                                        // [4][128][400] bf16
  u16* wsK  = (u16*)((char*)d_ws + (size_t)B_N * C_N * NKP * 2); // [4][400][128] bf16
  u16* wsW  = (u16*)((char*)d_ws + (size_t)2 * B_N * C_N * NKP * 2); // [128][128] bf16

  pool_kernel<<<512, 1024, 0, stream>>>(x5, W_out, wsK, wsKT, wsW, out);

  hipFuncSetAttribute((const void*)attn_kernel,
                      hipFuncAttributeMaxDynamicSharedMemorySize, LDS_BYTES);
  attn_kernel<<<B_N * 512, 256, LDS_BYTES, stream>>>(x5, wsK, wsKT, wsW, b_out, out);
}